// Round 2
// baseline (3272.898 us; speedup 1.0000x reference)
//
#include <hip/hip_runtime.h>

#define DIM 768
#define NBLK 4
#define BS 192
#define BATCH 8
#define HH 64
#define WW 64
#define KH 33                  // W/2+1 bins
#define NPTS (BATCH*HH*KH)     // 16896 frequency points
#define TWOPI_OVER_64 0.0981747704246810387f

typedef __attribute__((ext_vector_type(8))) short short8;
typedef __attribute__((ext_vector_type(4))) float floatx4;

static __device__ __forceinline__ short f2bs(float f) {
  union { float f; unsigned int i; } v; v.f = f;
  unsigned int x = v.i;
  return (short)((x + 0x7fffu + ((x >> 16) & 1u)) >> 16);
}

// ---------------------------------------------------------------------------
// Kernel 1: bias GEMM  out[m,n] = sum_k x[m,k]*bias_w[n,k] + bias_b[n]
// fp32 inputs converted RNE->bf16, MFMA 16x16x32. Block = 4 waves, 64x64 tile.
// ---------------------------------------------------------------------------
__global__ __launch_bounds__(256) void k_bias_gemm(
    const float* __restrict__ X, const float* __restrict__ Wt,
    const float* __restrict__ bb, float* __restrict__ out)
{
  const int wave = threadIdx.x >> 6;
  const int lane = threadIdx.x & 63;
  const int qm = lane & 15;
  const int quad = lane >> 4;
  const int m0 = blockIdx.x * 64 + wave * 16;
  const int n0 = blockIdx.y * 64;

  floatx4 acc0 = {0.f,0.f,0.f,0.f}, acc1 = {0.f,0.f,0.f,0.f};
  floatx4 acc2 = {0.f,0.f,0.f,0.f}, acc3 = {0.f,0.f,0.f,0.f};

  const float* ap = X  + (size_t)(m0 + qm) * DIM + quad * 8;
  const float* bp = Wt + (size_t)(n0 + qm) * DIM + quad * 8;

  #pragma unroll 1
  for (int k0 = 0; k0 < DIM; k0 += 32) {
    short8 a, w0, w1, w2, w3;
    #pragma unroll
    for (int j = 0; j < 8; ++j) {
      a[j]  = f2bs(ap[k0 + j]);
      w0[j] = f2bs(bp[k0 + j]);
      w1[j] = f2bs(bp[16*DIM + k0 + j]);
      w2[j] = f2bs(bp[32*DIM + k0 + j]);
      w3[j] = f2bs(bp[48*DIM + k0 + j]);
    }
    acc0 = __builtin_amdgcn_mfma_f32_16x16x32_bf16(a, w0, acc0, 0, 0, 0);
    acc1 = __builtin_amdgcn_mfma_f32_16x16x32_bf16(a, w1, acc1, 0, 0, 0);
    acc2 = __builtin_amdgcn_mfma_f32_16x16x32_bf16(a, w2, acc2, 0, 0, 0);
    acc3 = __builtin_amdgcn_mfma_f32_16x16x32_bf16(a, w3, acc3, 0, 0, 0);
  }
  floatx4 accs[4] = {acc0, acc1, acc2, acc3};
  #pragma unroll
  for (int j = 0; j < 4; ++j) {
    const int col = n0 + j*16 + qm;
    const float bias = bb[col];
    #pragma unroll
    for (int r = 0; r < 4; ++r) {
      const int row = m0 + quad*4 + r;
      out[(size_t)row * DIM + col] = accs[j][r] + bias;
    }
  }
}

// ---------------------------------------------------------------------------
// Kernel 2: row rFFT along w (real -> 33 complex bins), unnormalized.
// One thread per (b,h,c). S layout: [b][h][k][c], c contiguous.
// ---------------------------------------------------------------------------
__global__ __launch_bounds__(256) void k_rfft_w(
    const float* __restrict__ X,
    float* __restrict__ Sr, float* __restrict__ Si)
{
  __shared__ float2 tw[64];
  const int t = threadIdx.x;
  if (t < 64) { float s, c; sincosf((float)t * TWOPI_OVER_64, &s, &c); tw[t] = make_float2(c, s); }
  __syncthreads();

  const int bh = blockIdx.x;                 // b*64+h
  const int c = blockIdx.y * 256 + t;
  const float* xp = X + (size_t)bh * (WW*DIM) + c;

  float xv[64];
  #pragma unroll
  for (int w = 0; w < 64; ++w) xv[w] = xp[(size_t)w * DIM];

  const size_t obase = (size_t)bh * (KH*DIM) + c;
  #pragma unroll 1
  for (int k = 0; k <= 32; ++k) {
    float re = 0.f, im = 0.f;
    #pragma unroll
    for (int w = 0; w < 64; ++w) {
      float2 tt = tw[(w * k) & 63];
      re += xv[w] * tt.x;                    // cos
      im -= xv[w] * tt.y;                    // -sin (e^{-i theta})
    }
    Sr[obase + (size_t)k * DIM] = re;
    Si[obase + (size_t)k * DIM] = im;
  }
}

// ---------------------------------------------------------------------------
// Kernels 3/5: 64-pt complex DFT along h, in-place per (b,k,c) column.
// SGN=-1: forward (scale 1/64 for ortho 2D fwd). SGN=+1: inverse (scale 1).
// ---------------------------------------------------------------------------
template<int SGN>
__global__ __launch_bounds__(256) void k_fft_h(
    float* __restrict__ Sr, float* __restrict__ Si, float scale)
{
  __shared__ float2 tw[64];
  const int t = threadIdx.x;
  if (t < 64) { float s, c; sincosf((float)t * TWOPI_OVER_64, &s, &c); tw[t] = make_float2(c, s); }
  __syncthreads();

  const int b = blockIdx.x / KH;
  const int k = blockIdx.x % KH;
  const int c = blockIdx.y * 256 + t;
  const size_t hstride = (size_t)KH * DIM;
  const size_t base = ((size_t)b * HH * KH + k) * DIM + c;

  float sr[64], si[64];
  #pragma unroll
  for (int h = 0; h < 64; ++h) {
    sr[h] = Sr[base + h * hstride];
    si[h] = Si[base + h * hstride];
  }
  #pragma unroll 1
  for (int hp = 0; hp < 64; ++hp) {
    float ar = 0.f, ai = 0.f;
    #pragma unroll
    for (int h = 0; h < 64; ++h) {
      float2 tt = tw[(h * hp) & 63];
      if (SGN < 0) { ar += sr[h]*tt.x + si[h]*tt.y; ai += si[h]*tt.x - sr[h]*tt.y; }
      else         { ar += sr[h]*tt.x - si[h]*tt.y; ai += si[h]*tt.x + sr[h]*tt.y; }
    }
    Sr[base + hp * hstride] = ar * scale;
    Si[base + hp * hstride] = ai * scale;
  }
}

// ---------------------------------------------------------------------------
// Kernel 4: block-complex 2-layer MLP per frequency point, in-place on S.
// Block: 192 threads (thread = output channel), 32 points per block, one nb.
// Faithful to reference: i2 uses the NEW r2; ReLU per part on layer 1.
// ---------------------------------------------------------------------------
__global__ __launch_bounds__(192) void k_mix(
    float* __restrict__ Sr, float* __restrict__ Si,
    const float* __restrict__ w1, const float* __restrict__ b1,
    const float* __restrict__ w2, const float* __restrict__ b2)
{
  __shared__ float Ar[32][BS];
  __shared__ float Ai[32][BS];
  const int t = threadIdx.x;
  const int nb = blockIdx.y;
  const size_t rowbase = (size_t)blockIdx.x * 32 * DIM + nb * BS + t;

  #pragma unroll 1
  for (int p = 0; p < 32; ++p) {
    Ar[p][t] = Sr[rowbase + (size_t)p * DIM];
    Ai[p][t] = Si[rowbase + (size_t)p * DIM];
  }
  __syncthreads();

  float accr[32], acci[32];
  #pragma unroll
  for (int p = 0; p < 32; ++p) { accr[p] = 0.f; acci[p] = 0.f; }

  // ---- layer 1: r1 = relu(xr@w1r - xi@w1i + b1r), i1 = relu(xr@w1i + xi@w1r + b1i)
  {
    const float* wr_p = w1 + (size_t)(0*NBLK + nb) * BS * BS + t;
    const float* wi_p = w1 + (size_t)(1*NBLK + nb) * BS * BS + t;
    #pragma unroll 1
    for (int d = 0; d < BS; d += 2) {
      const float wr0 = wr_p[(size_t)d * BS];
      const float wi0 = wi_p[(size_t)d * BS];
      const float wr1 = wr_p[(size_t)(d+1) * BS];
      const float wi1 = wi_p[(size_t)(d+1) * BS];
      #pragma unroll
      for (int p = 0; p < 32; ++p) {
        float2 xr = *(const float2*)&Ar[p][d];
        float2 xi = *(const float2*)&Ai[p][d];
        accr[p] += xr.x*wr0 - xi.x*wi0 + xr.y*wr1 - xi.y*wi1;
        acci[p] += xr.x*wi0 + xi.x*wr0 + xr.y*wi1 + xi.y*wr1;
      }
    }
  }
  const float b1r = b1[(0*NBLK + nb)*BS + t];
  const float b1i = b1[(1*NBLK + nb)*BS + t];
  #pragma unroll
  for (int p = 0; p < 32; ++p) {
    accr[p] = fmaxf(accr[p] + b1r, 0.f);
    acci[p] = fmaxf(acci[p] + b1i, 0.f);
  }
  __syncthreads();
  #pragma unroll
  for (int p = 0; p < 32; ++p) { Ar[p][t] = accr[p]; Ai[p][t] = acci[p]; }  // r1, i1
  __syncthreads();

  const float* w2r_p = w2 + (size_t)(0*NBLK + nb) * BS * BS + t;
  const float* w2i_p = w2 + (size_t)(1*NBLK + nb) * BS * BS + t;

  // ---- layer 2a: r2 = r1@w2r - i1@w2i + b2r
  #pragma unroll
  for (int p = 0; p < 32; ++p) accr[p] = 0.f;
  #pragma unroll 1
  for (int d = 0; d < BS; d += 2) {
    const float wr0 = w2r_p[(size_t)d * BS];
    const float wi0 = w2i_p[(size_t)d * BS];
    const float wr1 = w2r_p[(size_t)(d+1) * BS];
    const float wi1 = w2i_p[(size_t)(d+1) * BS];
    #pragma unroll
    for (int p = 0; p < 32; ++p) {
      float2 r1v = *(const float2*)&Ar[p][d];
      float2 i1v = *(const float2*)&Ai[p][d];
      accr[p] += r1v.x*wr0 - i1v.x*wi0 + r1v.y*wr1 - i1v.y*wi1;
    }
  }
  const float b2r = b2[(0*NBLK + nb)*BS + t];
  #pragma unroll
  for (int p = 0; p < 32; ++p) accr[p] += b2r;
  __syncthreads();
  #pragma unroll
  for (int p = 0; p < 32; ++p) Ar[p][t] = accr[p];   // r2 replaces r1 (i1 kept)
  __syncthreads();

  // ---- layer 2b: i2 = r2@w2i + i1@w2r + b2i   (uses NEW r2 — reference quirk)
  #pragma unroll
  for (int p = 0; p < 32; ++p) acci[p] = 0.f;
  #pragma unroll 1
  for (int d = 0; d < BS; d += 2) {
    const float wr0 = w2r_p[(size_t)d * BS];
    const float wi0 = w2i_p[(size_t)d * BS];
    const float wr1 = w2r_p[(size_t)(d+1) * BS];
    const float wi1 = w2i_p[(size_t)(d+1) * BS];
    #pragma unroll
    for (int p = 0; p < 32; ++p) {
      float2 r2v = *(const float2*)&Ar[p][d];
      float2 i1v = *(const float2*)&Ai[p][d];
      acci[p] += r2v.x*wi0 + i1v.x*wr0 + r2v.y*wi1 + i1v.y*wr1;
    }
  }
  const float b2i = b2[(1*NBLK + nb)*BS + t];
  #pragma unroll
  for (int p = 0; p < 32; ++p) acci[p] += b2i;

  #pragma unroll 1
  for (int p = 0; p < 32; ++p) {
    Sr[rowbase + (size_t)p * DIM] = accr[p];   // r2
    Si[rowbase + (size_t)p * DIM] = acci[p];   // i2
  }
}

// ---------------------------------------------------------------------------
// Kernel 6: c2r inverse along k (33 bins -> 64 reals), + bias partial in d_out.
// out = (1/64) * [ g0 + (-1)^w g32 + sum_{k=1..31} 2(gr cos - gi sin) ] + bias
// (sin(0)=sin(pi w)=0 reproduces pocketfft's ignore-imag DC/Nyquist semantics)
// ---------------------------------------------------------------------------
__global__ __launch_bounds__(256) void k_irfft_w(
    const float* __restrict__ Sr, const float* __restrict__ Si,
    float* __restrict__ out)
{
  __shared__ float2 tw[64];
  const int t = threadIdx.x;
  if (t < 64) { float s, c; sincosf((float)t * TWOPI_OVER_64, &s, &c); tw[t] = make_float2(c, s); }
  __syncthreads();

  const int bh = blockIdx.x;
  const int c = blockIdx.y * 256 + t;
  const size_t base = (size_t)bh * (KH*DIM) + c;

  float gr[33], gi[33];
  #pragma unroll
  for (int k = 0; k <= 32; ++k) {
    gr[k] = Sr[base + (size_t)k * DIM];
    gi[k] = Si[base + (size_t)k * DIM];
  }
  const size_t obase = (size_t)bh * (WW*DIM) + c;
  #pragma unroll 1
  for (int w = 0; w < 64; ++w) {
    float acc = gr[0] + ((w & 1) ? -gr[32] : gr[32]);
    #pragma unroll
    for (int k = 1; k < 32; ++k) {
      float2 tt = tw[(w * k) & 63];
      acc += 2.f * (gr[k]*tt.x - gi[k]*tt.y);
    }
    const size_t oi = obase + (size_t)w * DIM;
    const float prev = out[oi];                    // bias partial from k_bias_gemm
    out[oi] = prev + acc * (1.0f/64.0f);
  }
}

// ---------------------------------------------------------------------------
extern "C" void kernel_launch(void* const* d_in, const int* in_sizes, int n_in,
                              void* d_out, int out_size, void* d_ws, size_t ws_size,
                              hipStream_t stream) {
  const float* x  = (const float*)d_in[0];
  const float* w1 = (const float*)d_in[1];
  const float* b1 = (const float*)d_in[2];
  const float* w2 = (const float*)d_in[3];
  const float* b2 = (const float*)d_in[4];
  const float* bw = (const float*)d_in[5];
  const float* bb = (const float*)d_in[6];
  float* out = (float*)d_out;

  float* Sr = (float*)d_ws;
  float* Si = Sr + (size_t)NPTS * DIM;

  // 1) bias = x @ bias_w^T + bias_b  -> d_out (fp32 partial)
  k_bias_gemm<<<dim3(32768/64, DIM/64), 256, 0, stream>>>(x, bw, bb, out);
  // 2) forward rfft along w
  k_rfft_w<<<dim3(BATCH*HH, 3), 256, 0, stream>>>(x, Sr, Si);
  // 3) forward fft along h (ortho scale 1/64 for the 2D forward)
  k_fft_h<-1><<<dim3(BATCH*KH, 3), 256, 0, stream>>>(Sr, Si, 1.0f/64.0f);
  // 4) block-complex MLP mixing, in place
  k_mix<<<dim3(NPTS/32, NBLK), 192, 0, stream>>>(Sr, Si, w1, b1, w2, b2);
  // 5) inverse fft along h (unnormalized; ortho 1/64 applied in stage 6)
  k_fft_h<+1><<<dim3(BATCH*KH, 3), 256, 0, stream>>>(Sr, Si, 1.0f);
  // 6) c2r inverse along k + add bias partial -> final fp32 output
  k_irfft_w<<<dim3(BATCH*HH, 3), 256, 0, stream>>>(Sr, Si, out);
}

// Round 3
// 1822.756 us; speedup vs baseline: 1.7956x; 1.7956x over previous
//
#include <hip/hip_runtime.h>

#define DIM 768
#define NBLK 4
#define BS 192
#define BATCH 8
#define HH 64
#define WW 64
#define KH 33                  // W/2+1 bins
#define NPTS (BATCH*HH*KH)     // 16896 frequency points
#define TWOPI_OVER_64 0.0981747704246810387f
#define LROW 200               // LDS row stride in bf16 (400B: 16B-aligned, 2-way banks)

typedef __attribute__((ext_vector_type(8))) short short8;
typedef __attribute__((ext_vector_type(4))) short short4v;
typedef __attribute__((ext_vector_type(4))) float floatx4;

static __device__ __forceinline__ short f2bs(float f) {
  union { float f; unsigned int i; } v; v.f = f;
  unsigned int x = v.i;
  return (short)((x + 0x7fffu + ((x >> 16) & 1u)) >> 16);
}

// ---------------------------------------------------------------------------
// Kernel 1: bias GEMM  out[m,n] = sum_k x[m,k]*bias_w[n,k] + bias_b[n]
// fp32 inputs converted RNE->bf16, MFMA 16x16x32. Block = 4 waves, 64x64 tile.
// ---------------------------------------------------------------------------
__global__ __launch_bounds__(256) void k_bias_gemm(
    const float* __restrict__ X, const float* __restrict__ Wt,
    const float* __restrict__ bb, float* __restrict__ out)
{
  const int wave = threadIdx.x >> 6;
  const int lane = threadIdx.x & 63;
  const int qm = lane & 15;
  const int quad = lane >> 4;
  const int m0 = blockIdx.x * 64 + wave * 16;
  const int n0 = blockIdx.y * 64;

  floatx4 acc0 = {0.f,0.f,0.f,0.f}, acc1 = {0.f,0.f,0.f,0.f};
  floatx4 acc2 = {0.f,0.f,0.f,0.f}, acc3 = {0.f,0.f,0.f,0.f};

  const float* ap = X  + (size_t)(m0 + qm) * DIM + quad * 8;
  const float* bp = Wt + (size_t)(n0 + qm) * DIM + quad * 8;

  #pragma unroll 1
  for (int k0 = 0; k0 < DIM; k0 += 32) {
    short8 a, w0, w1, w2, w3;
    #pragma unroll
    for (int j = 0; j < 8; ++j) {
      a[j]  = f2bs(ap[k0 + j]);
      w0[j] = f2bs(bp[k0 + j]);
      w1[j] = f2bs(bp[16*DIM + k0 + j]);
      w2[j] = f2bs(bp[32*DIM + k0 + j]);
      w3[j] = f2bs(bp[48*DIM + k0 + j]);
    }
    acc0 = __builtin_amdgcn_mfma_f32_16x16x32_bf16(a, w0, acc0, 0, 0, 0);
    acc1 = __builtin_amdgcn_mfma_f32_16x16x32_bf16(a, w1, acc1, 0, 0, 0);
    acc2 = __builtin_amdgcn_mfma_f32_16x16x32_bf16(a, w2, acc2, 0, 0, 0);
    acc3 = __builtin_amdgcn_mfma_f32_16x16x32_bf16(a, w3, acc3, 0, 0, 0);
  }
  floatx4 accs[4] = {acc0, acc1, acc2, acc3};
  #pragma unroll
  for (int j = 0; j < 4; ++j) {
    const int col = n0 + j*16 + qm;
    const float bias = bb[col];
    #pragma unroll
    for (int r = 0; r < 4; ++r) {
      const int row = m0 + quad*4 + r;
      out[(size_t)row * DIM + col] = accs[j][r] + bias;
    }
  }
}

// ---------------------------------------------------------------------------
// Kernel 2: row rFFT along w (real -> 33 complex bins), unnormalized.
// ---------------------------------------------------------------------------
__global__ __launch_bounds__(256) void k_rfft_w(
    const float* __restrict__ X,
    float* __restrict__ Sr, float* __restrict__ Si)
{
  __shared__ float2 tw[64];
  const int t = threadIdx.x;
  if (t < 64) { float s, c; sincosf((float)t * TWOPI_OVER_64, &s, &c); tw[t] = make_float2(c, s); }
  __syncthreads();

  const int bh = blockIdx.x;                 // b*64+h
  const int c = blockIdx.y * 256 + t;
  const float* xp = X + (size_t)bh * (WW*DIM) + c;

  float xv[64];
  #pragma unroll
  for (int w = 0; w < 64; ++w) xv[w] = xp[(size_t)w * DIM];

  const size_t obase = (size_t)bh * (KH*DIM) + c;
  #pragma unroll 1
  for (int k = 0; k <= 32; ++k) {
    float re = 0.f, im = 0.f;
    #pragma unroll
    for (int w = 0; w < 64; ++w) {
      float2 tt = tw[(w * k) & 63];
      re += xv[w] * tt.x;
      im -= xv[w] * tt.y;
    }
    Sr[obase + (size_t)k * DIM] = re;
    Si[obase + (size_t)k * DIM] = im;
  }
}

// ---------------------------------------------------------------------------
// Kernels 3/5: 64-pt complex DFT along h, in-place per (b,k,c) column.
// ---------------------------------------------------------------------------
template<int SGN>
__global__ __launch_bounds__(256) void k_fft_h(
    float* __restrict__ Sr, float* __restrict__ Si, float scale)
{
  __shared__ float2 tw[64];
  const int t = threadIdx.x;
  if (t < 64) { float s, c; sincosf((float)t * TWOPI_OVER_64, &s, &c); tw[t] = make_float2(c, s); }
  __syncthreads();

  const int b = blockIdx.x / KH;
  const int k = blockIdx.x % KH;
  const int c = blockIdx.y * 256 + t;
  const size_t hstride = (size_t)KH * DIM;
  const size_t base = ((size_t)b * HH * KH + k) * DIM + c;

  float sr[64], si[64];
  #pragma unroll
  for (int h = 0; h < 64; ++h) {
    sr[h] = Sr[base + h * hstride];
    si[h] = Si[base + h * hstride];
  }
  #pragma unroll 1
  for (int hp = 0; hp < 64; ++hp) {
    float ar = 0.f, ai = 0.f;
    #pragma unroll
    for (int h = 0; h < 64; ++h) {
      float2 tt = tw[(h * hp) & 63];
      if (SGN < 0) { ar += sr[h]*tt.x + si[h]*tt.y; ai += si[h]*tt.x - sr[h]*tt.y; }
      else         { ar += sr[h]*tt.x - si[h]*tt.y; ai += si[h]*tt.x + sr[h]*tt.y; }
    }
    Sr[base + hp * hstride] = ar * scale;
    Si[base + hp * hstride] = ai * scale;
  }
}

// ---------------------------------------------------------------------------
// Kernel P: transpose + convert mixing weights to bf16 B^T fragments.
// 6 arrays, each [nb][n_out][d] bf16:
//   0: +w1r^T  1: +w1i^T  2: -w1i^T  3: +w2r^T  4: +w2i^T  5: -w2i^T
// ---------------------------------------------------------------------------
__global__ __launch_bounds__(256) void k_prep_w(
    const float* __restrict__ w1, const float* __restrict__ w2,
    short* __restrict__ Wout)
{
  const int arr = blockIdx.y;
  const int i = blockIdx.x * 256 + threadIdx.x;    // 0 .. NBLK*BS*BS-1
  const int nb = i / (BS*BS);
  const int rem = i % (BS*BS);
  const int n = rem / BS;
  const int d = rem % BS;
  const float* src = (arr < 3) ? w1 : w2;
  const int j = ((arr % 3) == 0) ? 0 : 1;
  const float s = ((arr % 3) == 2) ? -1.f : 1.f;
  const float v = s * src[((size_t)(j*NBLK + nb) * BS + d) * BS + n];
  Wout[(size_t)arr * (NBLK*BS*BS) + i] = f2bs(v);
}

// ---------------------------------------------------------------------------
// Kernel 4 (v2): block-complex 2-layer MLP via MFMA bf16, fp32 accumulate.
// Block 256 = 4 waves; M-tile 64 points; wave w owns n-cols [48w, 48w+48).
// LDS round-trips transform C-layout -> A-layout between GEMMs.
// Faithful to reference: i2 uses NEW r2; ReLU per part on layer 1.
// ---------------------------------------------------------------------------
__global__ __launch_bounds__(256) void k_mix2(
    float* __restrict__ Sr, float* __restrict__ Si,
    const short* __restrict__ WT,
    const float* __restrict__ b1, const float* __restrict__ b2)
{
  __shared__ short Ar[64 * LROW];
  __shared__ short Ai[64 * LROW];
  const int t = threadIdx.x;
  const int wave = t >> 6, lane = t & 63;
  const int qm = lane & 15, quad = lane >> 4;
  const int nb = blockIdx.y;
  const int row0 = blockIdx.x * 64;

  const int WSZ = NBLK * BS * BS;
  const short* W1R  = WT;
  const short* W1I  = WT + 1 * WSZ;
  const short* W1IN = WT + 2 * WSZ;
  const short* W2R  = WT + 3 * WSZ;
  const short* W2I  = WT + 4 * WSZ;
  const short* W2IN = WT + 5 * WSZ;

  // ---- stage Xr, Xi -> bf16 LDS (A-layout: [row][d], row stride LROW)
  {
    const float4* Sr4 = (const float4*)Sr;
    const float4* Si4 = (const float4*)Si;
    #pragma unroll
    for (int it = 0; it < 12; ++it) {
      const int i = t + it * 256;                 // 0 .. 64*48-1
      const int r = i / 48, c4 = i % 48;
      const size_t g = (size_t)(row0 + r) * (DIM/4) + nb * 48 + c4;
      const float4 vr = Sr4[g], vi = Si4[g];
      short4v pr = { f2bs(vr.x), f2bs(vr.y), f2bs(vr.z), f2bs(vr.w) };
      short4v pi = { f2bs(vi.x), f2bs(vi.y), f2bs(vi.z), f2bs(vi.w) };
      *(short4v*)&Ar[r * LROW + c4 * 4] = pr;
      *(short4v*)&Ai[r * LROW + c4 * 4] = pi;
    }
  }
  __syncthreads();

  int nl[3];
  size_t wb[3];
  #pragma unroll
  for (int nt = 0; nt < 3; ++nt) {
    nl[nt] = wave * 48 + nt * 16 + qm;
    wb[nt] = (size_t)(nb * BS + nl[nt]) * BS + quad * 8;
  }
  const floatx4 zero = {0.f, 0.f, 0.f, 0.f};

  // ---- layer 1: R1 = relu(Xr·W1r + Xi·(-W1i) + b1r), I1 = relu(Xr·W1i + Xi·W1r + b1i)
  floatx4 aR[4][3], aI[4][3];
  #pragma unroll
  for (int ms = 0; ms < 4; ++ms)
    #pragma unroll
    for (int nt = 0; nt < 3; ++nt) { aR[ms][nt] = zero; aI[ms][nt] = zero; }

  #pragma unroll 1
  for (int k0 = 0; k0 < BS; k0 += 32) {
    short8 xr[4], xi[4];
    #pragma unroll
    for (int ms = 0; ms < 4; ++ms) {
      const int a = (ms*16 + qm) * LROW + k0 + quad * 8;
      xr[ms] = *(const short8*)&Ar[a];
      xi[ms] = *(const short8*)&Ai[a];
    }
    #pragma unroll
    for (int nt = 0; nt < 3; ++nt) {
      const short8 br  = *(const short8*)&W1R [wb[nt] + k0];
      const short8 bi  = *(const short8*)&W1I [wb[nt] + k0];
      const short8 bin = *(const short8*)&W1IN[wb[nt] + k0];
      #pragma unroll
      for (int ms = 0; ms < 4; ++ms) {
        aR[ms][nt] = __builtin_amdgcn_mfma_f32_16x16x32_bf16(xr[ms], br,  aR[ms][nt], 0,0,0);
        aR[ms][nt] = __builtin_amdgcn_mfma_f32_16x16x32_bf16(xi[ms], bin, aR[ms][nt], 0,0,0);
        aI[ms][nt] = __builtin_amdgcn_mfma_f32_16x16x32_bf16(xr[ms], bi,  aI[ms][nt], 0,0,0);
        aI[ms][nt] = __builtin_amdgcn_mfma_f32_16x16x32_bf16(xi[ms], br,  aI[ms][nt], 0,0,0);
      }
    }
  }
  __syncthreads();   // all Xr/Xi reads done -> safe to overwrite
  #pragma unroll
  for (int nt = 0; nt < 3; ++nt) {
    const float b1r = b1[nb * BS + nl[nt]];
    const float b1i = b1[(NBLK + nb) * BS + nl[nt]];
    #pragma unroll
    for (int ms = 0; ms < 4; ++ms)
      #pragma unroll
      for (int r = 0; r < 4; ++r) {
        const int row = ms*16 + quad*4 + r;
        Ar[row * LROW + nl[nt]] = f2bs(fmaxf(aR[ms][nt][r] + b1r, 0.f));
        Ai[row * LROW + nl[nt]] = f2bs(fmaxf(aI[ms][nt][r] + b1i, 0.f));
      }
  }
  __syncthreads();

  // ---- layer 2a: R2 = R1·W2r + I1·(-W2i) + b2r
  floatx4 aR2[4][3];
  #pragma unroll
  for (int ms = 0; ms < 4; ++ms)
    #pragma unroll
    for (int nt = 0; nt < 3; ++nt) aR2[ms][nt] = zero;

  #pragma unroll 1
  for (int k0 = 0; k0 < BS; k0 += 32) {
    short8 r1[4], i1[4];
    #pragma unroll
    for (int ms = 0; ms < 4; ++ms) {
      const int a = (ms*16 + qm) * LROW + k0 + quad * 8;
      r1[ms] = *(const short8*)&Ar[a];
      i1[ms] = *(const short8*)&Ai[a];
    }
    #pragma unroll
    for (int nt = 0; nt < 3; ++nt) {
      const short8 br  = *(const short8*)&W2R [wb[nt] + k0];
      const short8 bin = *(const short8*)&W2IN[wb[nt] + k0];
      #pragma unroll
      for (int ms = 0; ms < 4; ++ms) {
        aR2[ms][nt] = __builtin_amdgcn_mfma_f32_16x16x32_bf16(r1[ms], br,  aR2[ms][nt], 0,0,0);
        aR2[ms][nt] = __builtin_amdgcn_mfma_f32_16x16x32_bf16(i1[ms], bin, aR2[ms][nt], 0,0,0);
      }
    }
  }
  __syncthreads();   // R1 reads done -> safe to overwrite Ar with R2
  #pragma unroll
  for (int nt = 0; nt < 3; ++nt) {
    const float b2r = b2[nb * BS + nl[nt]];
    #pragma unroll
    for (int ms = 0; ms < 4; ++ms)
      #pragma unroll
      for (int r = 0; r < 4; ++r) {
        const int row = ms*16 + quad*4 + r;
        const float R2 = aR2[ms][nt][r] + b2r;
        Sr[(size_t)(row0 + row) * DIM + nb * BS + nl[nt]] = R2;   // final real out
        Ar[row * LROW + nl[nt]] = f2bs(R2);                        // feed layer 2b
      }
  }
  __syncthreads();

  // ---- layer 2b: I2 = R2·W2i + I1·W2r + b2i  (NEW r2 — reference quirk)
  floatx4 aI2[4][3];
  #pragma unroll
  for (int ms = 0; ms < 4; ++ms)
    #pragma unroll
    for (int nt = 0; nt < 3; ++nt) aI2[ms][nt] = zero;

  #pragma unroll 1
  for (int k0 = 0; k0 < BS; k0 += 32) {
    short8 r2[4], i1[4];
    #pragma unroll
    for (int ms = 0; ms < 4; ++ms) {
      const int a = (ms*16 + qm) * LROW + k0 + quad * 8;
      r2[ms] = *(const short8*)&Ar[a];
      i1[ms] = *(const short8*)&Ai[a];
    }
    #pragma unroll
    for (int nt = 0; nt < 3; ++nt) {
      const short8 bi = *(const short8*)&W2I[wb[nt] + k0];
      const short8 br = *(const short8*)&W2R[wb[nt] + k0];
      #pragma unroll
      for (int ms = 0; ms < 4; ++ms) {
        aI2[ms][nt] = __builtin_amdgcn_mfma_f32_16x16x32_bf16(r2[ms], bi, aI2[ms][nt], 0,0,0);
        aI2[ms][nt] = __builtin_amdgcn_mfma_f32_16x16x32_bf16(i1[ms], br, aI2[ms][nt], 0,0,0);
      }
    }
  }
  #pragma unroll
  for (int nt = 0; nt < 3; ++nt) {
    const float b2i = b2[(NBLK + nb) * BS + nl[nt]];
    #pragma unroll
    for (int ms = 0; ms < 4; ++ms)
      #pragma unroll
      for (int r = 0; r < 4; ++r) {
        const int row = ms*16 + quad*4 + r;
        Si[(size_t)(row0 + row) * DIM + nb * BS + nl[nt]] = aI2[ms][nt][r] + b2i;
      }
  }
}

// ---------------------------------------------------------------------------
// Kernel 6: c2r inverse along k (33 bins -> 64 reals), + bias partial in d_out.
// ---------------------------------------------------------------------------
__global__ __launch_bounds__(256) void k_irfft_w(
    const float* __restrict__ Sr, const float* __restrict__ Si,
    float* __restrict__ out)
{
  __shared__ float2 tw[64];
  const int t = threadIdx.x;
  if (t < 64) { float s, c; sincosf((float)t * TWOPI_OVER_64, &s, &c); tw[t] = make_float2(c, s); }
  __syncthreads();

  const int bh = blockIdx.x;
  const int c = blockIdx.y * 256 + t;
  const size_t base = (size_t)bh * (KH*DIM) + c;

  float gr[33], gi[33];
  #pragma unroll
  for (int k = 0; k <= 32; ++k) {
    gr[k] = Sr[base + (size_t)k * DIM];
    gi[k] = Si[base + (size_t)k * DIM];
  }
  const size_t obase = (size_t)bh * (WW*DIM) + c;
  #pragma unroll 1
  for (int w = 0; w < 64; ++w) {
    float acc = gr[0] + ((w & 1) ? -gr[32] : gr[32]);
    #pragma unroll
    for (int k = 1; k < 32; ++k) {
      float2 tt = tw[(w * k) & 63];
      acc += 2.f * (gr[k]*tt.x - gi[k]*tt.y);
    }
    const size_t oi = obase + (size_t)w * DIM;
    const float prev = out[oi];
    out[oi] = prev + acc * (1.0f/64.0f);
  }
}

// ---------------------------------------------------------------------------
extern "C" void kernel_launch(void* const* d_in, const int* in_sizes, int n_in,
                              void* d_out, int out_size, void* d_ws, size_t ws_size,
                              hipStream_t stream) {
  const float* x  = (const float*)d_in[0];
  const float* w1 = (const float*)d_in[1];
  const float* b1 = (const float*)d_in[2];
  const float* w2 = (const float*)d_in[3];
  const float* b2 = (const float*)d_in[4];
  const float* bw = (const float*)d_in[5];
  const float* bb = (const float*)d_in[6];
  float* out = (float*)d_out;

  float* Sr = (float*)d_ws;
  float* Si = Sr + (size_t)NPTS * DIM;
  short* WT = (short*)(Si + (size_t)NPTS * DIM);

  // P) transpose+convert mixing weights to bf16 fragments
  k_prep_w<<<dim3((NBLK*BS*BS)/256, 6), 256, 0, stream>>>(w1, w2, WT);
  // 1) bias = x @ bias_w^T + bias_b  -> d_out (fp32 partial)
  k_bias_gemm<<<dim3(32768/64, DIM/64), 256, 0, stream>>>(x, bw, bb, out);
  // 2) forward rfft along w
  k_rfft_w<<<dim3(BATCH*HH, 3), 256, 0, stream>>>(x, Sr, Si);
  // 3) forward fft along h (ortho scale 1/64 for the 2D forward)
  k_fft_h<-1><<<dim3(BATCH*KH, 3), 256, 0, stream>>>(Sr, Si, 1.0f/64.0f);
  // 4) block-complex MLP mixing via MFMA, in place
  k_mix2<<<dim3(NPTS/64, NBLK), 256, 0, stream>>>(Sr, Si, WT, b1, b2);
  // 5) inverse fft along h (unnormalized; ortho 1/64 applied in stage 6)
  k_fft_h<+1><<<dim3(BATCH*KH, 3), 256, 0, stream>>>(Sr, Si, 1.0f);
  // 6) c2r inverse along k + add bias partial -> final fp32 output
  k_irfft_w<<<dim3(BATCH*HH, 3), 256, 0, stream>>>(Sr, Si, out);
}

// Round 4
// 1300.581 us; speedup vs baseline: 2.5165x; 1.4015x over previous
//
#include <hip/hip_runtime.h>

#define DIM 768
#define NBLK 4
#define BS 192
#define BATCH 8
#define HH 64
#define WW 64
#define KH 33                  // W/2+1 bins
#define NPTS (BATCH*HH*KH)     // 16896 frequency points
#define TWOPI_OVER_64 0.0981747704246810387f
#define LROW 200               // LDS row stride in bf16 (400B: 16B-aligned, 2-way banks)

typedef __attribute__((ext_vector_type(8))) short short8;
typedef __attribute__((ext_vector_type(4))) short short4v;
typedef __attribute__((ext_vector_type(4))) float floatx4;

static __device__ __forceinline__ short f2bs(float f) {
  union { float f; unsigned int i; } v; v.f = f;
  unsigned int x = v.i;
  return (short)((x + 0x7fffu + ((x >> 16) & 1u)) >> 16);
}
// round-half-up bf16 pack (1 ulp worst-case on exact ties only; 2 VALU ops)
static __device__ __forceinline__ short f2bs_fast(float f) {
  union { float f; unsigned int i; } v; v.f = f;
  return (short)((v.i + 0x8000u) >> 16);
}

// ---------------------------------------------------------------------------
// Kernel 1 (v2): bias GEMM  out[m,n] = sum_k x[m,k]*bias_w[n,k] + bias_b[n]
// m97 structure: 128x128 tile, BK=32, coalesced fp32->bf16 LDS staging,
// 4 waves x (4x4) 16x16x32 bf16 MFMA fragments, fp32 accumulate.
// ---------------------------------------------------------------------------
__global__ __launch_bounds__(256) void k_bias_gemm2(
    const float* __restrict__ X, const float* __restrict__ Wt,
    const float* __restrict__ bb, float* __restrict__ out)
{
  __shared__ short As[128 * 32];
  __shared__ short Bs[128 * 32];
  const int t = threadIdx.x;
  const int wave = t >> 6, lane = t & 63;
  const int qm = lane & 15, quad = lane >> 4;
  const int wr = (wave >> 1) * 64;      // wave row quadrant
  const int wc = (wave & 1) * 64;       // wave col quadrant
  const int m0 = blockIdx.x * 128, n0 = blockIdx.y * 128;

  floatx4 acc[4][4];
  const floatx4 zero = {0.f, 0.f, 0.f, 0.f};
  #pragma unroll
  for (int ms = 0; ms < 4; ++ms)
    #pragma unroll
    for (int ns = 0; ns < 4; ++ns) acc[ms][ns] = zero;

  const float4* X4 = (const float4*)X;
  const float4* W4 = (const float4*)Wt;

  #pragma unroll 1
  for (int k0 = 0; k0 < DIM; k0 += 32) {
    __syncthreads();           // previous compute done before overwrite
    #pragma unroll
    for (int j = 0; j < 2; ++j) {
      const int c = t + j * 256;          // 0..511
      const int r = c >> 2, ko = (c & 3) * 8;
      const size_t ga = (size_t)(m0 + r) * (DIM/4) + (k0 + ko) / 4;
      const size_t gb = (size_t)(n0 + r) * (DIM/4) + (k0 + ko) / 4;
      const float4 a0 = X4[ga], a1 = X4[ga + 1];
      const float4 b0 = W4[gb], b1 = W4[gb + 1];
      short8 pa = { f2bs_fast(a0.x), f2bs_fast(a0.y), f2bs_fast(a0.z), f2bs_fast(a0.w),
                    f2bs_fast(a1.x), f2bs_fast(a1.y), f2bs_fast(a1.z), f2bs_fast(a1.w) };
      short8 pb = { f2bs_fast(b0.x), f2bs_fast(b0.y), f2bs_fast(b0.z), f2bs_fast(b0.w),
                    f2bs_fast(b1.x), f2bs_fast(b1.y), f2bs_fast(b1.z), f2bs_fast(b1.w) };
      *(short8*)&As[r * 32 + ko] = pa;
      *(short8*)&Bs[r * 32 + ko] = pb;
    }
    __syncthreads();

    short8 af[4], bf[4];
    #pragma unroll
    for (int ms = 0; ms < 4; ++ms)
      af[ms] = *(const short8*)&As[(wr + ms*16 + qm) * 32 + quad * 8];
    #pragma unroll
    for (int ns = 0; ns < 4; ++ns)
      bf[ns] = *(const short8*)&Bs[(wc + ns*16 + qm) * 32 + quad * 8];
    #pragma unroll
    for (int ms = 0; ms < 4; ++ms)
      #pragma unroll
      for (int ns = 0; ns < 4; ++ns)
        acc[ms][ns] = __builtin_amdgcn_mfma_f32_16x16x32_bf16(af[ms], bf[ns], acc[ms][ns], 0, 0, 0);
  }

  #pragma unroll
  for (int ns = 0; ns < 4; ++ns) {
    const int col = n0 + wc + ns*16 + qm;
    const float bias = bb[col];
    #pragma unroll
    for (int ms = 0; ms < 4; ++ms)
      #pragma unroll
      for (int r = 0; r < 4; ++r) {
        const int row = m0 + wr + ms*16 + quad*4 + r;
        out[(size_t)row * DIM + col] = acc[ms][ns][r] + bias;
      }
  }
}

// ---------------------------------------------------------------------------
// Kernel 2: row rFFT along w (real -> 33 complex bins), unnormalized.
// ---------------------------------------------------------------------------
__global__ __launch_bounds__(256) void k_rfft_w(
    const float* __restrict__ X,
    float* __restrict__ Sr, float* __restrict__ Si)
{
  __shared__ float2 tw[64];
  const int t = threadIdx.x;
  if (t < 64) { float s, c; sincosf((float)t * TWOPI_OVER_64, &s, &c); tw[t] = make_float2(c, s); }
  __syncthreads();

  const int bh = blockIdx.x;                 // b*64+h
  const int c = blockIdx.y * 256 + t;
  const float* xp = X + (size_t)bh * (WW*DIM) + c;

  float xv[64];
  #pragma unroll
  for (int w = 0; w < 64; ++w) xv[w] = xp[(size_t)w * DIM];

  const size_t obase = (size_t)bh * (KH*DIM) + c;
  #pragma unroll 1
  for (int k = 0; k <= 32; ++k) {
    float re = 0.f, im = 0.f;
    #pragma unroll
    for (int w = 0; w < 64; ++w) {
      float2 tt = tw[(w * k) & 63];
      re += xv[w] * tt.x;
      im -= xv[w] * tt.y;
    }
    Sr[obase + (size_t)k * DIM] = re;
    Si[obase + (size_t)k * DIM] = im;
  }
}

// ---------------------------------------------------------------------------
// Kernels 3/5: 64-pt complex DFT along h, in-place per (b,k,c) column.
// ---------------------------------------------------------------------------
template<int SGN>
__global__ __launch_bounds__(256) void k_fft_h(
    float* __restrict__ Sr, float* __restrict__ Si, float scale)
{
  __shared__ float2 tw[64];
  const int t = threadIdx.x;
  if (t < 64) { float s, c; sincosf((float)t * TWOPI_OVER_64, &s, &c); tw[t] = make_float2(c, s); }
  __syncthreads();

  const int b = blockIdx.x / KH;
  const int k = blockIdx.x % KH;
  const int c = blockIdx.y * 256 + t;
  const size_t hstride = (size_t)KH * DIM;
  const size_t base = ((size_t)b * HH * KH + k) * DIM + c;

  float sr[64], si[64];
  #pragma unroll
  for (int h = 0; h < 64; ++h) {
    sr[h] = Sr[base + h * hstride];
    si[h] = Si[base + h * hstride];
  }
  #pragma unroll 1
  for (int hp = 0; hp < 64; ++hp) {
    float ar = 0.f, ai = 0.f;
    #pragma unroll
    for (int h = 0; h < 64; ++h) {
      float2 tt = tw[(h * hp) & 63];
      if (SGN < 0) { ar += sr[h]*tt.x + si[h]*tt.y; ai += si[h]*tt.x - sr[h]*tt.y; }
      else         { ar += sr[h]*tt.x - si[h]*tt.y; ai += si[h]*tt.x + sr[h]*tt.y; }
    }
    Sr[base + hp * hstride] = ar * scale;
    Si[base + hp * hstride] = ai * scale;
  }
}

// ---------------------------------------------------------------------------
// Kernel P: transpose + convert mixing weights to bf16 B^T fragments.
// 6 arrays, each [nb][n_out][d] bf16:
//   0: +w1r^T  1: +w1i^T  2: -w1i^T  3: +w2r^T  4: +w2i^T  5: -w2i^T
// ---------------------------------------------------------------------------
__global__ __launch_bounds__(256) void k_prep_w(
    const float* __restrict__ w1, const float* __restrict__ w2,
    short* __restrict__ Wout)
{
  const int arr = blockIdx.y;
  const int i = blockIdx.x * 256 + threadIdx.x;    // 0 .. NBLK*BS*BS-1
  const int nb = i / (BS*BS);
  const int rem = i % (BS*BS);
  const int n = rem / BS;
  const int d = rem % BS;
  const float* src = (arr < 3) ? w1 : w2;
  const int j = ((arr % 3) == 0) ? 0 : 1;
  const float s = ((arr % 3) == 2) ? -1.f : 1.f;
  const float v = s * src[((size_t)(j*NBLK + nb) * BS + d) * BS + n];
  Wout[(size_t)arr * (NBLK*BS*BS) + i] = f2bs(v);
}

// ---------------------------------------------------------------------------
// Kernel 4 (v2): block-complex 2-layer MLP via MFMA bf16, fp32 accumulate.
// ---------------------------------------------------------------------------
__global__ __launch_bounds__(256) void k_mix2(
    float* __restrict__ Sr, float* __restrict__ Si,
    const short* __restrict__ WT,
    const float* __restrict__ b1, const float* __restrict__ b2)
{
  __shared__ short Ar[64 * LROW];
  __shared__ short Ai[64 * LROW];
  const int t = threadIdx.x;
  const int wave = t >> 6, lane = t & 63;
  const int qm = lane & 15, quad = lane >> 4;
  const int nb = blockIdx.y;
  const int row0 = blockIdx.x * 64;

  const int WSZ = NBLK * BS * BS;
  const short* W1R  = WT;
  const short* W1I  = WT + 1 * WSZ;
  const short* W1IN = WT + 2 * WSZ;
  const short* W2R  = WT + 3 * WSZ;
  const short* W2I  = WT + 4 * WSZ;
  const short* W2IN = WT + 5 * WSZ;

  // ---- stage Xr, Xi -> bf16 LDS (A-layout: [row][d], row stride LROW)
  {
    const float4* Sr4 = (const float4*)Sr;
    const float4* Si4 = (const float4*)Si;
    #pragma unroll
    for (int it = 0; it < 12; ++it) {
      const int i = t + it * 256;                 // 0 .. 64*48-1
      const int r = i / 48, c4 = i % 48;
      const size_t g = (size_t)(row0 + r) * (DIM/4) + nb * 48 + c4;
      const float4 vr = Sr4[g], vi = Si4[g];
      short4v pr = { f2bs(vr.x), f2bs(vr.y), f2bs(vr.z), f2bs(vr.w) };
      short4v pi = { f2bs(vi.x), f2bs(vi.y), f2bs(vi.z), f2bs(vi.w) };
      *(short4v*)&Ar[r * LROW + c4 * 4] = pr;
      *(short4v*)&Ai[r * LROW + c4 * 4] = pi;
    }
  }
  __syncthreads();

  int nl[3];
  size_t wb[3];
  #pragma unroll
  for (int nt = 0; nt < 3; ++nt) {
    nl[nt] = wave * 48 + nt * 16 + qm;
    wb[nt] = (size_t)(nb * BS + nl[nt]) * BS + quad * 8;
  }
  const floatx4 zero = {0.f, 0.f, 0.f, 0.f};

  // ---- layer 1
  floatx4 aR[4][3], aI[4][3];
  #pragma unroll
  for (int ms = 0; ms < 4; ++ms)
    #pragma unroll
    for (int nt = 0; nt < 3; ++nt) { aR[ms][nt] = zero; aI[ms][nt] = zero; }

  #pragma unroll 1
  for (int k0 = 0; k0 < BS; k0 += 32) {
    short8 xr[4], xi[4];
    #pragma unroll
    for (int ms = 0; ms < 4; ++ms) {
      const int a = (ms*16 + qm) * LROW + k0 + quad * 8;
      xr[ms] = *(const short8*)&Ar[a];
      xi[ms] = *(const short8*)&Ai[a];
    }
    #pragma unroll
    for (int nt = 0; nt < 3; ++nt) {
      const short8 br  = *(const short8*)&W1R [wb[nt] + k0];
      const short8 bi  = *(const short8*)&W1I [wb[nt] + k0];
      const short8 bin = *(const short8*)&W1IN[wb[nt] + k0];
      #pragma unroll
      for (int ms = 0; ms < 4; ++ms) {
        aR[ms][nt] = __builtin_amdgcn_mfma_f32_16x16x32_bf16(xr[ms], br,  aR[ms][nt], 0,0,0);
        aR[ms][nt] = __builtin_amdgcn_mfma_f32_16x16x32_bf16(xi[ms], bin, aR[ms][nt], 0,0,0);
        aI[ms][nt] = __builtin_amdgcn_mfma_f32_16x16x32_bf16(xr[ms], bi,  aI[ms][nt], 0,0,0);
        aI[ms][nt] = __builtin_amdgcn_mfma_f32_16x16x32_bf16(xi[ms], br,  aI[ms][nt], 0,0,0);
      }
    }
  }
  __syncthreads();
  #pragma unroll
  for (int nt = 0; nt < 3; ++nt) {
    const float b1r = b1[nb * BS + nl[nt]];
    const float b1i = b1[(NBLK + nb) * BS + nl[nt]];
    #pragma unroll
    for (int ms = 0; ms < 4; ++ms)
      #pragma unroll
      for (int r = 0; r < 4; ++r) {
        const int row = ms*16 + quad*4 + r;
        Ar[row * LROW + nl[nt]] = f2bs(fmaxf(aR[ms][nt][r] + b1r, 0.f));
        Ai[row * LROW + nl[nt]] = f2bs(fmaxf(aI[ms][nt][r] + b1i, 0.f));
      }
  }
  __syncthreads();

  // ---- layer 2a: R2 = R1·W2r + I1·(-W2i) + b2r
  floatx4 aR2[4][3];
  #pragma unroll
  for (int ms = 0; ms < 4; ++ms)
    #pragma unroll
    for (int nt = 0; nt < 3; ++nt) aR2[ms][nt] = zero;

  #pragma unroll 1
  for (int k0 = 0; k0 < BS; k0 += 32) {
    short8 r1[4], i1[4];
    #pragma unroll
    for (int ms = 0; ms < 4; ++ms) {
      const int a = (ms*16 + qm) * LROW + k0 + quad * 8;
      r1[ms] = *(const short8*)&Ar[a];
      i1[ms] = *(const short8*)&Ai[a];
    }
    #pragma unroll
    for (int nt = 0; nt < 3; ++nt) {
      const short8 br  = *(const short8*)&W2R [wb[nt] + k0];
      const short8 bin = *(const short8*)&W2IN[wb[nt] + k0];
      #pragma unroll
      for (int ms = 0; ms < 4; ++ms) {
        aR2[ms][nt] = __builtin_amdgcn_mfma_f32_16x16x32_bf16(r1[ms], br,  aR2[ms][nt], 0,0,0);
        aR2[ms][nt] = __builtin_amdgcn_mfma_f32_16x16x32_bf16(i1[ms], bin, aR2[ms][nt], 0,0,0);
      }
    }
  }
  __syncthreads();
  #pragma unroll
  for (int nt = 0; nt < 3; ++nt) {
    const float b2r = b2[nb * BS + nl[nt]];
    #pragma unroll
    for (int ms = 0; ms < 4; ++ms)
      #pragma unroll
      for (int r = 0; r < 4; ++r) {
        const int row = ms*16 + quad*4 + r;
        const float R2 = aR2[ms][nt][r] + b2r;
        Sr[(size_t)(row0 + row) * DIM + nb * BS + nl[nt]] = R2;
        Ar[row * LROW + nl[nt]] = f2bs(R2);
      }
  }
  __syncthreads();

  // ---- layer 2b: I2 = R2·W2i + I1·W2r + b2i  (NEW r2 — reference quirk)
  floatx4 aI2[4][3];
  #pragma unroll
  for (int ms = 0; ms < 4; ++ms)
    #pragma unroll
    for (int nt = 0; nt < 3; ++nt) aI2[ms][nt] = zero;

  #pragma unroll 1
  for (int k0 = 0; k0 < BS; k0 += 32) {
    short8 r2[4], i1[4];
    #pragma unroll
    for (int ms = 0; ms < 4; ++ms) {
      const int a = (ms*16 + qm) * LROW + k0 + quad * 8;
      r2[ms] = *(const short8*)&Ar[a];
      i1[ms] = *(const short8*)&Ai[a];
    }
    #pragma unroll
    for (int nt = 0; nt < 3; ++nt) {
      const short8 bi = *(const short8*)&W2I[wb[nt] + k0];
      const short8 br = *(const short8*)&W2R[wb[nt] + k0];
      #pragma unroll
      for (int ms = 0; ms < 4; ++ms) {
        aI2[ms][nt] = __builtin_amdgcn_mfma_f32_16x16x32_bf16(r2[ms], bi, aI2[ms][nt], 0,0,0);
        aI2[ms][nt] = __builtin_amdgcn_mfma_f32_16x16x32_bf16(i1[ms], br, aI2[ms][nt], 0,0,0);
      }
    }
  }
  #pragma unroll
  for (int nt = 0; nt < 3; ++nt) {
    const float b2i = b2[(NBLK + nb) * BS + nl[nt]];
    #pragma unroll
    for (int ms = 0; ms < 4; ++ms)
      #pragma unroll
      for (int r = 0; r < 4; ++r) {
        const int row = ms*16 + quad*4 + r;
        Si[(size_t)(row0 + row) * DIM + nb * BS + nl[nt]] = aI2[ms][nt][r] + b2i;
      }
  }
}

// ---------------------------------------------------------------------------
// Kernel 6: c2r inverse along k (33 bins -> 64 reals), + bias partial in d_out.
// ---------------------------------------------------------------------------
__global__ __launch_bounds__(256) void k_irfft_w(
    const float* __restrict__ Sr, const float* __restrict__ Si,
    float* __restrict__ out)
{
  __shared__ float2 tw[64];
  const int t = threadIdx.x;
  if (t < 64) { float s, c; sincosf((float)t * TWOPI_OVER_64, &s, &c); tw[t] = make_float2(c, s); }
  __syncthreads();

  const int bh = blockIdx.x;
  const int c = blockIdx.y * 256 + t;
  const size_t base = (size_t)bh * (KH*DIM) + c;

  float gr[33], gi[33];
  #pragma unroll
  for (int k = 0; k <= 32; ++k) {
    gr[k] = Sr[base + (size_t)k * DIM];
    gi[k] = Si[base + (size_t)k * DIM];
  }
  const size_t obase = (size_t)bh * (WW*DIM) + c;
  #pragma unroll 1
  for (int w = 0; w < 64; ++w) {
    float acc = gr[0] + ((w & 1) ? -gr[32] : gr[32]);
    #pragma unroll
    for (int k = 1; k < 32; ++k) {
      float2 tt = tw[(w * k) & 63];
      acc += 2.f * (gr[k]*tt.x - gi[k]*tt.y);
    }
    const size_t oi = obase + (size_t)w * DIM;
    const float prev = out[oi];
    out[oi] = prev + acc * (1.0f/64.0f);
  }
}

// ---------------------------------------------------------------------------
extern "C" void kernel_launch(void* const* d_in, const int* in_sizes, int n_in,
                              void* d_out, int out_size, void* d_ws, size_t ws_size,
                              hipStream_t stream) {
  const float* x  = (const float*)d_in[0];
  const float* w1 = (const float*)d_in[1];
  const float* b1 = (const float*)d_in[2];
  const float* w2 = (const float*)d_in[3];
  const float* b2 = (const float*)d_in[4];
  const float* bw = (const float*)d_in[5];
  const float* bb = (const float*)d_in[6];
  float* out = (float*)d_out;

  float* Sr = (float*)d_ws;
  float* Si = Sr + (size_t)NPTS * DIM;
  short* WT = (short*)(Si + (size_t)NPTS * DIM);

  // P) transpose+convert mixing weights to bf16 fragments
  k_prep_w<<<dim3((NBLK*BS*BS)/256, 6), 256, 0, stream>>>(w1, w2, WT);
  // 1) bias = x @ bias_w^T + bias_b  -> d_out (fp32 partial)
  k_bias_gemm2<<<dim3(32768/128, DIM/128), 256, 0, stream>>>(x, bw, bb, out);
  // 2) forward rfft along w
  k_rfft_w<<<dim3(BATCH*HH, 3), 256, 0, stream>>>(x, Sr, Si);
  // 3) forward fft along h (ortho scale 1/64 for the 2D forward)
  k_fft_h<-1><<<dim3(BATCH*KH, 3), 256, 0, stream>>>(Sr, Si, 1.0f/64.0f);
  // 4) block-complex MLP mixing via MFMA, in place
  k_mix2<<<dim3(NPTS/64, NBLK), 256, 0, stream>>>(Sr, Si, WT, b1, b2);
  // 5) inverse fft along h (unnormalized; ortho 1/64 applied in stage 6)
  k_fft_h<+1><<<dim3(BATCH*KH, 3), 256, 0, stream>>>(Sr, Si, 1.0f);
  // 6) c2r inverse along k + add bias partial -> final fp32 output
  k_irfft_w<<<dim3(BATCH*HH, 3), 256, 0, stream>>>(Sr, Si, out);
}

// Round 5
// 784.917 us; speedup vs baseline: 4.1697x; 1.6570x over previous
//
#include <hip/hip_runtime.h>

#define DIM 768
#define NBLK 4
#define BS 192
#define BATCH 8
#define HH 64
#define WW 64
#define KH 33                  // W/2+1 bins
#define NPTS (BATCH*HH*KH)     // 16896 frequency points
#define TWOPI_OVER_64 0.0981747704246810387f
#define LROW 200               // k_mix2 LDS row stride in bf16

typedef __attribute__((ext_vector_type(8))) short short8;
typedef __attribute__((ext_vector_type(4))) short short4v;
typedef __attribute__((ext_vector_type(4))) float floatx4;

static __device__ __forceinline__ short f2bs(float f) {
  union { float f; unsigned int i; } v; v.f = f;
  unsigned int x = v.i;
  return (short)((x + 0x7fffu + ((x >> 16) & 1u)) >> 16);
}
static __device__ __forceinline__ float bs2f(short s) {
  union { unsigned int i; float f; } v; v.i = ((unsigned int)(unsigned short)s) << 16; return v.f;
}
// round-half-up bf16 pack (cheap)
static __device__ __forceinline__ short f2bs_fast(float f) {
  union { float f; unsigned int i; } v; v.f = f;
  return (short)((v.i + 0x8000u) >> 16);
}

// ---------------------------------------------------------------------------
// Kernel 1 (v2): bias GEMM  out[m,n] = sum_k x[m,k]*bias_w[n,k] + bias_b[n]
// ---------------------------------------------------------------------------
__global__ __launch_bounds__(256) void k_bias_gemm2(
    const float* __restrict__ X, const float* __restrict__ Wt,
    const float* __restrict__ bb, float* __restrict__ out)
{
  __shared__ short As[128 * 32];
  __shared__ short Bs[128 * 32];
  const int t = threadIdx.x;
  const int wave = t >> 6, lane = t & 63;
  const int qm = lane & 15, quad = lane >> 4;
  const int wr = (wave >> 1) * 64;
  const int wc = (wave & 1) * 64;
  const int m0 = blockIdx.x * 128, n0 = blockIdx.y * 128;

  floatx4 acc[4][4];
  const floatx4 zero = {0.f, 0.f, 0.f, 0.f};
  #pragma unroll
  for (int ms = 0; ms < 4; ++ms)
    #pragma unroll
    for (int ns = 0; ns < 4; ++ns) acc[ms][ns] = zero;

  const float4* X4 = (const float4*)X;
  const float4* W4 = (const float4*)Wt;

  #pragma unroll 1
  for (int k0 = 0; k0 < DIM; k0 += 32) {
    __syncthreads();
    #pragma unroll
    for (int j = 0; j < 2; ++j) {
      const int c = t + j * 256;
      const int r = c >> 2, ko = (c & 3) * 8;
      const size_t ga = (size_t)(m0 + r) * (DIM/4) + (k0 + ko) / 4;
      const size_t gb = (size_t)(n0 + r) * (DIM/4) + (k0 + ko) / 4;
      const float4 a0 = X4[ga], a1 = X4[ga + 1];
      const float4 b0 = W4[gb], b1 = W4[gb + 1];
      short8 pa = { f2bs_fast(a0.x), f2bs_fast(a0.y), f2bs_fast(a0.z), f2bs_fast(a0.w),
                    f2bs_fast(a1.x), f2bs_fast(a1.y), f2bs_fast(a1.z), f2bs_fast(a1.w) };
      short8 pb = { f2bs_fast(b0.x), f2bs_fast(b0.y), f2bs_fast(b0.z), f2bs_fast(b0.w),
                    f2bs_fast(b1.x), f2bs_fast(b1.y), f2bs_fast(b1.z), f2bs_fast(b1.w) };
      *(short8*)&As[r * 32 + ko] = pa;
      *(short8*)&Bs[r * 32 + ko] = pb;
    }
    __syncthreads();

    short8 af[4], bf[4];
    #pragma unroll
    for (int ms = 0; ms < 4; ++ms)
      af[ms] = *(const short8*)&As[(wr + ms*16 + qm) * 32 + quad * 8];
    #pragma unroll
    for (int ns = 0; ns < 4; ++ns)
      bf[ns] = *(const short8*)&Bs[(wc + ns*16 + qm) * 32 + quad * 8];
    #pragma unroll
    for (int ms = 0; ms < 4; ++ms)
      #pragma unroll
      for (int ns = 0; ns < 4; ++ns)
        acc[ms][ns] = __builtin_amdgcn_mfma_f32_16x16x32_bf16(af[ms], bf[ns], acc[ms][ns], 0, 0, 0);
  }

  #pragma unroll
  for (int ns = 0; ns < 4; ++ns) {
    const int col = n0 + wc + ns*16 + qm;
    const float bias = bb[col];
    #pragma unroll
    for (int ms = 0; ms < 4; ++ms)
      #pragma unroll
      for (int r = 0; r < 4; ++r) {
        const int row = m0 + wr + ms*16 + quad*4 + r;
        out[(size_t)row * DIM + col] = acc[ms][ns][r] + bias;
      }
  }
}

// ---------------------------------------------------------------------------
// Kernel 2: row rFFT along w (real -> 33 complex bins), unnormalized.
// ---------------------------------------------------------------------------
__global__ __launch_bounds__(256) void k_rfft_w(
    const float* __restrict__ X,
    float* __restrict__ Sr, float* __restrict__ Si)
{
  __shared__ float2 tw[64];
  const int t = threadIdx.x;
  if (t < 64) { float s, c; sincosf((float)t * TWOPI_OVER_64, &s, &c); tw[t] = make_float2(c, s); }
  __syncthreads();

  const int bh = blockIdx.x;
  const int c = blockIdx.y * 256 + t;
  const float* xp = X + (size_t)bh * (WW*DIM) + c;

  float xv[64];
  #pragma unroll
  for (int w = 0; w < 64; ++w) xv[w] = xp[(size_t)w * DIM];

  const size_t obase = (size_t)bh * (KH*DIM) + c;
  #pragma unroll 1
  for (int k = 0; k <= 32; ++k) {
    float re = 0.f, im = 0.f;
    #pragma unroll
    for (int w = 0; w < 64; ++w) {
      float2 tt = tw[(w * k) & 63];
      re += xv[w] * tt.x;
      im -= xv[w] * tt.y;
    }
    Sr[obase + (size_t)k * DIM] = re;
    Si[obase + (size_t)k * DIM] = im;
  }
}

// ---------------------------------------------------------------------------
// Kernels 3/5 (v2): 64-pt DFT along h as MFMA GEMM: S'[hp,c] = sum_h T[hp,h] S[h,c].
// A = T (registers, hi/lo split bf16, scale folded), B = S^T (LDS bf16), per (b,k,c-slab).
// SGN=-1 fwd (e^{-i}), SGN=+1 inv (e^{+i}). In-place on Sr/Si.
// ---------------------------------------------------------------------------
template<int SGN>
__global__ __launch_bounds__(256) void k_fft_h_mfma(
    float* __restrict__ Sr, float* __restrict__ Si, float scale)
{
  __shared__ short Lr[96 * 72];   // [c][h], row stride 72 shorts (144 B, 16B-aligned)
  __shared__ short Li[96 * 72];
  const int t = threadIdx.x;
  const int wave = t >> 6, lane = t & 63;
  const int qm = lane & 15, quad = lane >> 4;
  const int bk = blockIdx.x;            // b*KH + k
  const int b = bk / KH, k = bk % KH;
  const int c0 = blockIdx.y * 96;
  const size_t hstride = (size_t)KH * DIM;
  const size_t base = ((size_t)b * HH * KH + k) * DIM;

  // ---- twiddle A-frags: m=hp (qm), k=h (quad*8+j+32kk); hi/lo split; scale folded
  short8 Trh[2], Trl[2], Tih[2], Til[2], TiNh[2], TiNl[2];
  const int hp_frag = wave * 16 + qm;
  #pragma unroll
  for (int kk = 0; kk < 2; ++kk) {
    #pragma unroll
    for (int j = 0; j < 8; ++j) {
      const int h = quad * 8 + j + kk * 32;
      const int ph = (hp_frag * h) & 63;
      float s, c;
      sincosf((float)ph * TWOPI_OVER_64, &s, &c);
      const float tr = c * scale;
      const float ti = (SGN < 0 ? -s : s) * scale;
      const short trh = f2bs(tr);
      const short trl = f2bs(tr - bs2f(trh));
      const short tih = f2bs(ti);
      const short til = f2bs(ti - bs2f(tih));
      Trh[kk][j] = trh;  Trl[kk][j] = trl;
      Tih[kk][j] = tih;  Til[kk][j] = til;
      TiNh[kk][j] = (short)(tih ^ (short)0x8000);
      TiNl[kk][j] = (short)(til ^ (short)0x8000);
    }
  }

  // ---- stage S-slab into LDS transposed [c][h] (bf16).
  // h-major cells: lane -> hd = lane&31 spans all banks => conflict-free b32 writes.
  #pragma unroll
  for (int it = 0; it < 3; ++it) {
    const int i = t + it * 256;         // 0..767
    const int hd = i & 31;              // h pair index
    const int c4 = i >> 5;              // 0..23 float4 column
    const size_t g0 = base + (size_t)(2*hd) * hstride + c0 + c4 * 4;
    const float4 ra = *(const float4*)&Sr[g0];
    const float4 rb = *(const float4*)&Sr[g0 + hstride];
    const float4 ia = *(const float4*)&Si[g0];
    const float4 ib = *(const float4*)&Si[g0 + hstride];
    const float raf[4] = {ra.x, ra.y, ra.z, ra.w};
    const float rbf[4] = {rb.x, rb.y, rb.z, rb.w};
    const float iaf[4] = {ia.x, ia.y, ia.z, ia.w};
    const float ibf[4] = {ib.x, ib.y, ib.z, ib.w};
    #pragma unroll
    for (int e = 0; e < 4; ++e) {
      const int d = (c4*4 + e) * 36 + hd;   // dword index (row stride 36 dwords)
      const unsigned pr = (unsigned)(unsigned short)f2bs(raf[e]) |
                          ((unsigned)(unsigned short)f2bs(rbf[e]) << 16);
      const unsigned pi = (unsigned)(unsigned short)f2bs(iaf[e]) |
                          ((unsigned)(unsigned short)f2bs(ibf[e]) << 16);
      ((unsigned*)Lr)[d] = pr;
      ((unsigned*)Li)[d] = pi;
    }
  }
  __syncthreads();

  // ---- compute: wave w -> hp-tile w; loop c-tiles
  const floatx4 zero = {0.f, 0.f, 0.f, 0.f};
  #pragma unroll 1
  for (int ct = 0; ct < 6; ++ct) {
    floatx4 Cr = zero, Ci = zero;
    #pragma unroll
    for (int kk = 0; kk < 2; ++kk) {
      const int a = (ct*16 + qm) * 72 + kk*32 + quad*8;
      const short8 sr = *(const short8*)&Lr[a];
      const short8 si = *(const short8*)&Li[a];
      Cr = __builtin_amdgcn_mfma_f32_16x16x32_bf16(Trh[kk],  sr, Cr, 0,0,0);
      Cr = __builtin_amdgcn_mfma_f32_16x16x32_bf16(Trl[kk],  sr, Cr, 0,0,0);
      Cr = __builtin_amdgcn_mfma_f32_16x16x32_bf16(TiNh[kk], si, Cr, 0,0,0);
      Cr = __builtin_amdgcn_mfma_f32_16x16x32_bf16(TiNl[kk], si, Cr, 0,0,0);
      Ci = __builtin_amdgcn_mfma_f32_16x16x32_bf16(Tih[kk],  sr, Ci, 0,0,0);
      Ci = __builtin_amdgcn_mfma_f32_16x16x32_bf16(Til[kk],  sr, Ci, 0,0,0);
      Ci = __builtin_amdgcn_mfma_f32_16x16x32_bf16(Trh[kk],  si, Ci, 0,0,0);
      Ci = __builtin_amdgcn_mfma_f32_16x16x32_bf16(Trl[kk],  si, Ci, 0,0,0);
    }
    #pragma unroll
    for (int r = 0; r < 4; ++r) {
      const int hpo = wave*16 + quad*4 + r;
      const size_t o = base + (size_t)hpo * hstride + c0 + ct*16 + qm;
      Sr[o] = Cr[r];
      Si[o] = Ci[r];
    }
  }
}

// ---------------------------------------------------------------------------
// Kernel P: transpose + convert mixing weights to bf16 B^T fragments.
// ---------------------------------------------------------------------------
__global__ __launch_bounds__(256) void k_prep_w(
    const float* __restrict__ w1, const float* __restrict__ w2,
    short* __restrict__ Wout)
{
  const int arr = blockIdx.y;
  const int i = blockIdx.x * 256 + threadIdx.x;
  const int nb = i / (BS*BS);
  const int rem = i % (BS*BS);
  const int n = rem / BS;
  const int d = rem % BS;
  const float* src = (arr < 3) ? w1 : w2;
  const int j = ((arr % 3) == 0) ? 0 : 1;
  const float s = ((arr % 3) == 2) ? -1.f : 1.f;
  const float v = s * src[((size_t)(j*NBLK + nb) * BS + d) * BS + n];
  Wout[(size_t)arr * (NBLK*BS*BS) + i] = f2bs(v);
}

// ---------------------------------------------------------------------------
// Kernel 4 (v2): block-complex 2-layer MLP via MFMA bf16, fp32 accumulate.
// ---------------------------------------------------------------------------
__global__ __launch_bounds__(256) void k_mix2(
    float* __restrict__ Sr, float* __restrict__ Si,
    const short* __restrict__ WT,
    const float* __restrict__ b1, const float* __restrict__ b2)
{
  __shared__ short Ar[64 * LROW];
  __shared__ short Ai[64 * LROW];
  const int t = threadIdx.x;
  const int wave = t >> 6, lane = t & 63;
  const int qm = lane & 15, quad = lane >> 4;
  const int nb = blockIdx.y;
  const int row0 = blockIdx.x * 64;

  const int WSZ = NBLK * BS * BS;
  const short* W1R  = WT;
  const short* W1I  = WT + 1 * WSZ;
  const short* W1IN = WT + 2 * WSZ;
  const short* W2R  = WT + 3 * WSZ;
  const short* W2I  = WT + 4 * WSZ;
  const short* W2IN = WT + 5 * WSZ;

  {
    const float4* Sr4 = (const float4*)Sr;
    const float4* Si4 = (const float4*)Si;
    #pragma unroll
    for (int it = 0; it < 12; ++it) {
      const int i = t + it * 256;
      const int r = i / 48, c4 = i % 48;
      const size_t g = (size_t)(row0 + r) * (DIM/4) + nb * 48 + c4;
      const float4 vr = Sr4[g], vi = Si4[g];
      short4v pr = { f2bs(vr.x), f2bs(vr.y), f2bs(vr.z), f2bs(vr.w) };
      short4v pi = { f2bs(vi.x), f2bs(vi.y), f2bs(vi.z), f2bs(vi.w) };
      *(short4v*)&Ar[r * LROW + c4 * 4] = pr;
      *(short4v*)&Ai[r * LROW + c4 * 4] = pi;
    }
  }
  __syncthreads();

  int nl[3];
  size_t wb[3];
  #pragma unroll
  for (int nt = 0; nt < 3; ++nt) {
    nl[nt] = wave * 48 + nt * 16 + qm;
    wb[nt] = (size_t)(nb * BS + nl[nt]) * BS + quad * 8;
  }
  const floatx4 zero = {0.f, 0.f, 0.f, 0.f};

  floatx4 aR[4][3], aI[4][3];
  #pragma unroll
  for (int ms = 0; ms < 4; ++ms)
    #pragma unroll
    for (int nt = 0; nt < 3; ++nt) { aR[ms][nt] = zero; aI[ms][nt] = zero; }

  #pragma unroll 1
  for (int k0 = 0; k0 < BS; k0 += 32) {
    short8 xr[4], xi[4];
    #pragma unroll
    for (int ms = 0; ms < 4; ++ms) {
      const int a = (ms*16 + qm) * LROW + k0 + quad * 8;
      xr[ms] = *(const short8*)&Ar[a];
      xi[ms] = *(const short8*)&Ai[a];
    }
    #pragma unroll
    for (int nt = 0; nt < 3; ++nt) {
      const short8 br  = *(const short8*)&W1R [wb[nt] + k0];
      const short8 bi  = *(const short8*)&W1I [wb[nt] + k0];
      const short8 bin = *(const short8*)&W1IN[wb[nt] + k0];
      #pragma unroll
      for (int ms = 0; ms < 4; ++ms) {
        aR[ms][nt] = __builtin_amdgcn_mfma_f32_16x16x32_bf16(xr[ms], br,  aR[ms][nt], 0,0,0);
        aR[ms][nt] = __builtin_amdgcn_mfma_f32_16x16x32_bf16(xi[ms], bin, aR[ms][nt], 0,0,0);
        aI[ms][nt] = __builtin_amdgcn_mfma_f32_16x16x32_bf16(xr[ms], bi,  aI[ms][nt], 0,0,0);
        aI[ms][nt] = __builtin_amdgcn_mfma_f32_16x16x32_bf16(xi[ms], br,  aI[ms][nt], 0,0,0);
      }
    }
  }
  __syncthreads();
  #pragma unroll
  for (int nt = 0; nt < 3; ++nt) {
    const float b1r = b1[nb * BS + nl[nt]];
    const float b1i = b1[(NBLK + nb) * BS + nl[nt]];
    #pragma unroll
    for (int ms = 0; ms < 4; ++ms)
      #pragma unroll
      for (int r = 0; r < 4; ++r) {
        const int row = ms*16 + quad*4 + r;
        Ar[row * LROW + nl[nt]] = f2bs(fmaxf(aR[ms][nt][r] + b1r, 0.f));
        Ai[row * LROW + nl[nt]] = f2bs(fmaxf(aI[ms][nt][r] + b1i, 0.f));
      }
  }
  __syncthreads();

  floatx4 aR2[4][3];
  #pragma unroll
  for (int ms = 0; ms < 4; ++ms)
    #pragma unroll
    for (int nt = 0; nt < 3; ++nt) aR2[ms][nt] = zero;

  #pragma unroll 1
  for (int k0 = 0; k0 < BS; k0 += 32) {
    short8 r1[4], i1[4];
    #pragma unroll
    for (int ms = 0; ms < 4; ++ms) {
      const int a = (ms*16 + qm) * LROW + k0 + quad * 8;
      r1[ms] = *(const short8*)&Ar[a];
      i1[ms] = *(const short8*)&Ai[a];
    }
    #pragma unroll
    for (int nt = 0; nt < 3; ++nt) {
      const short8 br  = *(const short8*)&W2R [wb[nt] + k0];
      const short8 bin = *(const short8*)&W2IN[wb[nt] + k0];
      #pragma unroll
      for (int ms = 0; ms < 4; ++ms) {
        aR2[ms][nt] = __builtin_amdgcn_mfma_f32_16x16x32_bf16(r1[ms], br,  aR2[ms][nt], 0,0,0);
        aR2[ms][nt] = __builtin_amdgcn_mfma_f32_16x16x32_bf16(i1[ms], bin, aR2[ms][nt], 0,0,0);
      }
    }
  }
  __syncthreads();
  #pragma unroll
  for (int nt = 0; nt < 3; ++nt) {
    const float b2r = b2[nb * BS + nl[nt]];
    #pragma unroll
    for (int ms = 0; ms < 4; ++ms)
      #pragma unroll
      for (int r = 0; r < 4; ++r) {
        const int row = ms*16 + quad*4 + r;
        const float R2 = aR2[ms][nt][r] + b2r;
        Sr[(size_t)(row0 + row) * DIM + nb * BS + nl[nt]] = R2;
        Ar[row * LROW + nl[nt]] = f2bs(R2);
      }
  }
  __syncthreads();

  floatx4 aI2[4][3];
  #pragma unroll
  for (int ms = 0; ms < 4; ++ms)
    #pragma unroll
    for (int nt = 0; nt < 3; ++nt) aI2[ms][nt] = zero;

  #pragma unroll 1
  for (int k0 = 0; k0 < BS; k0 += 32) {
    short8 r2[4], i1[4];
    #pragma unroll
    for (int ms = 0; ms < 4; ++ms) {
      const int a = (ms*16 + qm) * LROW + k0 + quad * 8;
      r2[ms] = *(const short8*)&Ar[a];
      i1[ms] = *(const short8*)&Ai[a];
    }
    #pragma unroll
    for (int nt = 0; nt < 3; ++nt) {
      const short8 bi = *(const short8*)&W2I[wb[nt] + k0];
      const short8 br = *(const short8*)&W2R[wb[nt] + k0];
      #pragma unroll
      for (int ms = 0; ms < 4; ++ms) {
        aI2[ms][nt] = __builtin_amdgcn_mfma_f32_16x16x32_bf16(r2[ms], bi, aI2[ms][nt], 0,0,0);
        aI2[ms][nt] = __builtin_amdgcn_mfma_f32_16x16x32_bf16(i1[ms], br, aI2[ms][nt], 0,0,0);
      }
    }
  }
  #pragma unroll
  for (int nt = 0; nt < 3; ++nt) {
    const float b2i = b2[(NBLK + nb) * BS + nl[nt]];
    #pragma unroll
    for (int ms = 0; ms < 4; ++ms)
      #pragma unroll
      for (int r = 0; r < 4; ++r) {
        const int row = ms*16 + quad*4 + r;
        Si[(size_t)(row0 + row) * DIM + nb * BS + nl[nt]] = aI2[ms][nt][r] + b2i;
      }
  }
}

// ---------------------------------------------------------------------------
// Kernel 6: c2r inverse along k (33 bins -> 64 reals), + bias partial in d_out.
// ---------------------------------------------------------------------------
__global__ __launch_bounds__(256) void k_irfft_w(
    const float* __restrict__ Sr, const float* __restrict__ Si,
    float* __restrict__ out)
{
  __shared__ float2 tw[64];
  const int t = threadIdx.x;
  if (t < 64) { float s, c; sincosf((float)t * TWOPI_OVER_64, &s, &c); tw[t] = make_float2(c, s); }
  __syncthreads();

  const int bh = blockIdx.x;
  const int c = blockIdx.y * 256 + t;
  const size_t base = (size_t)bh * (KH*DIM) + c;

  float gr[33], gi[33];
  #pragma unroll
  for (int k = 0; k <= 32; ++k) {
    gr[k] = Sr[base + (size_t)k * DIM];
    gi[k] = Si[base + (size_t)k * DIM];
  }
  const size_t obase = (size_t)bh * (WW*DIM) + c;
  #pragma unroll 1
  for (int w = 0; w < 64; ++w) {
    float acc = gr[0] + ((w & 1) ? -gr[32] : gr[32]);
    #pragma unroll
    for (int k = 1; k < 32; ++k) {
      float2 tt = tw[(w * k) & 63];
      acc += 2.f * (gr[k]*tt.x - gi[k]*tt.y);
    }
    const size_t oi = obase + (size_t)w * DIM;
    const float prev = out[oi];
    out[oi] = prev + acc * (1.0f/64.0f);
  }
}

// ---------------------------------------------------------------------------
extern "C" void kernel_launch(void* const* d_in, const int* in_sizes, int n_in,
                              void* d_out, int out_size, void* d_ws, size_t ws_size,
                              hipStream_t stream) {
  const float* x  = (const float*)d_in[0];
  const float* w1 = (const float*)d_in[1];
  const float* b1 = (const float*)d_in[2];
  const float* w2 = (const float*)d_in[3];
  const float* b2 = (const float*)d_in[4];
  const float* bw = (const float*)d_in[5];
  const float* bb = (const float*)d_in[6];
  float* out = (float*)d_out;

  float* Sr = (float*)d_ws;
  float* Si = Sr + (size_t)NPTS * DIM;
  short* WT = (short*)(Si + (size_t)NPTS * DIM);

  // P) transpose+convert mixing weights to bf16 fragments
  k_prep_w<<<dim3((NBLK*BS*BS)/256, 6), 256, 0, stream>>>(w1, w2, WT);
  // 1) bias = x @ bias_w^T + bias_b  -> d_out (fp32 partial)
  k_bias_gemm2<<<dim3(32768/128, DIM/128), 256, 0, stream>>>(x, bw, bb, out);
  // 2) forward rfft along w
  k_rfft_w<<<dim3(BATCH*HH, 3), 256, 0, stream>>>(x, Sr, Si);
  // 3) forward fft along h via MFMA (ortho scale 1/64 folded into twiddles)
  k_fft_h_mfma<-1><<<dim3(BATCH*KH, DIM/96), 256, 0, stream>>>(Sr, Si, 1.0f/64.0f);
  // 4) block-complex MLP mixing via MFMA, in place
  k_mix2<<<dim3(NPTS/64, NBLK), 256, 0, stream>>>(Sr, Si, WT, b1, b2);
  // 5) inverse fft along h via MFMA (unnormalized)
  k_fft_h_mfma<+1><<<dim3(BATCH*KH, DIM/96), 256, 0, stream>>>(Sr, Si, 1.0f);
  // 6) c2r inverse along k + add bias partial -> final fp32 output
  k_irfft_w<<<dim3(BATCH*HH, 3), 256, 0, stream>>>(Sr, Si, out);
}

// Round 6
// 610.695 us; speedup vs baseline: 5.3593x; 1.2853x over previous
//
#include <hip/hip_runtime.h>

#define DIM 768
#define NBLK 4
#define BS 192
#define BATCH 8
#define HH 64
#define WW 64
#define KH 33                  // W/2+1 bins
#define NPTS (BATCH*HH*KH)     // 16896 frequency points
#define TWOPI_OVER_64 0.0981747704246810387f
#define LROW 200               // k_mix2 LDS row stride in bf16

typedef __attribute__((ext_vector_type(8))) short short8;
typedef __attribute__((ext_vector_type(4))) short short4v;
typedef __attribute__((ext_vector_type(4))) float floatx4;

static __device__ __forceinline__ short f2bs(float f) {
  union { float f; unsigned int i; } v; v.f = f;
  unsigned int x = v.i;
  return (short)((x + 0x7fffu + ((x >> 16) & 1u)) >> 16);
}
static __device__ __forceinline__ float bs2f(short s) {
  union { unsigned int i; float f; } v; v.i = ((unsigned int)(unsigned short)s) << 16; return v.f;
}
static __device__ __forceinline__ short f2bs_fast(float f) {
  union { float f; unsigned int i; } v; v.f = f;
  return (short)((v.i + 0x8000u) >> 16);
}

// ---------------------------------------------------------------------------
// Kernel 1 (v2): bias GEMM  out[m,n] = sum_k x[m,k]*bias_w[n,k] + bias_b[n]
// ---------------------------------------------------------------------------
__global__ __launch_bounds__(256) void k_bias_gemm2(
    const float* __restrict__ X, const float* __restrict__ Wt,
    const float* __restrict__ bb, float* __restrict__ out)
{
  __shared__ short As[128 * 32];
  __shared__ short Bs[128 * 32];
  const int t = threadIdx.x;
  const int wave = t >> 6, lane = t & 63;
  const int qm = lane & 15, quad = lane >> 4;
  const int wr = (wave >> 1) * 64;
  const int wc = (wave & 1) * 64;
  const int m0 = blockIdx.x * 128, n0 = blockIdx.y * 128;

  floatx4 acc[4][4];
  const floatx4 zero = {0.f, 0.f, 0.f, 0.f};
  #pragma unroll
  for (int ms = 0; ms < 4; ++ms)
    #pragma unroll
    for (int ns = 0; ns < 4; ++ns) acc[ms][ns] = zero;

  const float4* X4 = (const float4*)X;
  const float4* W4 = (const float4*)Wt;

  #pragma unroll 1
  for (int k0 = 0; k0 < DIM; k0 += 32) {
    __syncthreads();
    #pragma unroll
    for (int j = 0; j < 2; ++j) {
      const int c = t + j * 256;
      const int r = c >> 2, ko = (c & 3) * 8;
      const size_t ga = (size_t)(m0 + r) * (DIM/4) + (k0 + ko) / 4;
      const size_t gb = (size_t)(n0 + r) * (DIM/4) + (k0 + ko) / 4;
      const float4 a0 = X4[ga], a1 = X4[ga + 1];
      const float4 b0 = W4[gb], b1 = W4[gb + 1];
      short8 pa = { f2bs_fast(a0.x), f2bs_fast(a0.y), f2bs_fast(a0.z), f2bs_fast(a0.w),
                    f2bs_fast(a1.x), f2bs_fast(a1.y), f2bs_fast(a1.z), f2bs_fast(a1.w) };
      short8 pb = { f2bs_fast(b0.x), f2bs_fast(b0.y), f2bs_fast(b0.z), f2bs_fast(b0.w),
                    f2bs_fast(b1.x), f2bs_fast(b1.y), f2bs_fast(b1.z), f2bs_fast(b1.w) };
      *(short8*)&As[r * 32 + ko] = pa;
      *(short8*)&Bs[r * 32 + ko] = pb;
    }
    __syncthreads();

    short8 af[4], bf[4];
    #pragma unroll
    for (int ms = 0; ms < 4; ++ms)
      af[ms] = *(const short8*)&As[(wr + ms*16 + qm) * 32 + quad * 8];
    #pragma unroll
    for (int ns = 0; ns < 4; ++ns)
      bf[ns] = *(const short8*)&Bs[(wc + ns*16 + qm) * 32 + quad * 8];
    #pragma unroll
    for (int ms = 0; ms < 4; ++ms)
      #pragma unroll
      for (int ns = 0; ns < 4; ++ns)
        acc[ms][ns] = __builtin_amdgcn_mfma_f32_16x16x32_bf16(af[ms], bf[ns], acc[ms][ns], 0, 0, 0);
  }

  #pragma unroll
  for (int ns = 0; ns < 4; ++ns) {
    const int col = n0 + wc + ns*16 + qm;
    const float bias = bb[col];
    #pragma unroll
    for (int ms = 0; ms < 4; ++ms)
      #pragma unroll
      for (int r = 0; r < 4; ++r) {
        const int row = m0 + wr + ms*16 + quad*4 + r;
        out[(size_t)row * DIM + col] = acc[ms][ns][r] + bias;
      }
  }
}

// ---------------------------------------------------------------------------
// Kernel 2 (v2): row rFFT along w as MFMA GEMM. S[k,c] = sum_w T[k,w] X[w,c].
// A = twiddles (hi/lo split, registers), B = X^T (LDS bf16). Unnormalized.
// M=33: waves 0-1 full tiles, wave 2 stores row 32 only, wave 3 idle.
// ---------------------------------------------------------------------------
__global__ __launch_bounds__(256) void k_rfft_w_mfma(
    const float* __restrict__ X,
    float* __restrict__ Sr, float* __restrict__ Si)
{
  __shared__ short Lx[96 * 72];   // [c][w], row stride 72 shorts
  const int t = threadIdx.x;
  const int wave = t >> 6, lane = t & 63;
  const int qm = lane & 15, quad = lane >> 4;
  const int bh = blockIdx.x;
  const int c0 = blockIdx.y * 96;
  const size_t xbase = (size_t)bh * (WW*DIM);
  const size_t obase = (size_t)bh * (KH*DIM);

  // stage X -> LDS transposed [c][w] bf16
  #pragma unroll
  for (int it = 0; it < 3; ++it) {
    const int i = t + it * 256;         // 0..767
    const int hd = i & 31;              // w-pair
    const int c4 = i >> 5;              // 0..23
    const size_t g0 = xbase + (size_t)(2*hd) * DIM + c0 + c4 * 4;
    const float4 ra = *(const float4*)&X[g0];
    const float4 rb = *(const float4*)&X[g0 + DIM];
    const float raf[4] = {ra.x, ra.y, ra.z, ra.w};
    const float rbf[4] = {rb.x, rb.y, rb.z, rb.w};
    #pragma unroll
    for (int e = 0; e < 4; ++e) {
      const int d = (c4*4 + e) * 36 + hd;
      ((unsigned*)Lx)[d] = (unsigned)(unsigned short)f2bs(raf[e]) |
                           ((unsigned)(unsigned short)f2bs(rbf[e]) << 16);
    }
  }

  // twiddle A-frags: m=k (qm), k=w (quad*8+j+32kk); e^{-i}, hi/lo split
  short8 Trh[2], Trl[2], Tih[2], Til[2];
  const int krow = wave * 16 + qm;
  #pragma unroll
  for (int kk = 0; kk < 2; ++kk) {
    #pragma unroll
    for (int j = 0; j < 8; ++j) {
      const int w = quad * 8 + j + kk * 32;
      const int ph = (krow * w) & 63;
      float s, c;
      sincosf((float)ph * TWOPI_OVER_64, &s, &c);
      const float tr = c, ti = -s;
      const short trh = f2bs(tr);
      const short tih = f2bs(ti);
      Trh[kk][j] = trh;  Trl[kk][j] = f2bs(tr - bs2f(trh));
      Tih[kk][j] = tih;  Til[kk][j] = f2bs(ti - bs2f(tih));
    }
  }
  __syncthreads();

  if (wave < 3) {
    const floatx4 zero = {0.f, 0.f, 0.f, 0.f};
    #pragma unroll 1
    for (int ct = 0; ct < 6; ++ct) {
      floatx4 Cr = zero, Ci = zero;
      #pragma unroll
      for (int kk = 0; kk < 2; ++kk) {
        const int a = (ct*16 + qm) * 72 + kk*32 + quad*8;
        const short8 xv = *(const short8*)&Lx[a];
        Cr = __builtin_amdgcn_mfma_f32_16x16x32_bf16(Trh[kk], xv, Cr, 0,0,0);
        Cr = __builtin_amdgcn_mfma_f32_16x16x32_bf16(Trl[kk], xv, Cr, 0,0,0);
        Ci = __builtin_amdgcn_mfma_f32_16x16x32_bf16(Tih[kk], xv, Ci, 0,0,0);
        Ci = __builtin_amdgcn_mfma_f32_16x16x32_bf16(Til[kk], xv, Ci, 0,0,0);
      }
      #pragma unroll
      for (int r = 0; r < 4; ++r) {
        const int ko = wave*16 + quad*4 + r;
        if (ko < KH) {
          const size_t o = obase + (size_t)ko * DIM + c0 + ct*16 + qm;
          Sr[o] = Cr[r];
          Si[o] = Ci[r];
        }
      }
    }
  }
}

// ---------------------------------------------------------------------------
// Kernels 3/5: 64-pt DFT along h as MFMA GEMM (validated r4 structure).
// ---------------------------------------------------------------------------
template<int SGN>
__global__ __launch_bounds__(256) void k_fft_h_mfma(
    float* __restrict__ Sr, float* __restrict__ Si, float scale)
{
  __shared__ short Lr[96 * 72];
  __shared__ short Li[96 * 72];
  const int t = threadIdx.x;
  const int wave = t >> 6, lane = t & 63;
  const int qm = lane & 15, quad = lane >> 4;
  const int bk = blockIdx.x;
  const int b = bk / KH, k = bk % KH;
  const int c0 = blockIdx.y * 96;
  const size_t hstride = (size_t)KH * DIM;
  const size_t base = ((size_t)b * HH * KH + k) * DIM;

  short8 Trh[2], Trl[2], Tih[2], Til[2], TiNh[2], TiNl[2];
  const int hp_frag = wave * 16 + qm;
  #pragma unroll
  for (int kk = 0; kk < 2; ++kk) {
    #pragma unroll
    for (int j = 0; j < 8; ++j) {
      const int h = quad * 8 + j + kk * 32;
      const int ph = (hp_frag * h) & 63;
      float s, c;
      sincosf((float)ph * TWOPI_OVER_64, &s, &c);
      const float tr = c * scale;
      const float ti = (SGN < 0 ? -s : s) * scale;
      const short trh = f2bs(tr);
      const short trl = f2bs(tr - bs2f(trh));
      const short tih = f2bs(ti);
      const short til = f2bs(ti - bs2f(tih));
      Trh[kk][j] = trh;  Trl[kk][j] = trl;
      Tih[kk][j] = tih;  Til[kk][j] = til;
      TiNh[kk][j] = (short)(tih ^ (short)0x8000);
      TiNl[kk][j] = (short)(til ^ (short)0x8000);
    }
  }

  #pragma unroll
  for (int it = 0; it < 3; ++it) {
    const int i = t + it * 256;
    const int hd = i & 31;
    const int c4 = i >> 5;
    const size_t g0 = base + (size_t)(2*hd) * hstride + c0 + c4 * 4;
    const float4 ra = *(const float4*)&Sr[g0];
    const float4 rb = *(const float4*)&Sr[g0 + hstride];
    const float4 ia = *(const float4*)&Si[g0];
    const float4 ib = *(const float4*)&Si[g0 + hstride];
    const float raf[4] = {ra.x, ra.y, ra.z, ra.w};
    const float rbf[4] = {rb.x, rb.y, rb.z, rb.w};
    const float iaf[4] = {ia.x, ia.y, ia.z, ia.w};
    const float ibf[4] = {ib.x, ib.y, ib.z, ib.w};
    #pragma unroll
    for (int e = 0; e < 4; ++e) {
      const int d = (c4*4 + e) * 36 + hd;
      const unsigned pr = (unsigned)(unsigned short)f2bs(raf[e]) |
                          ((unsigned)(unsigned short)f2bs(rbf[e]) << 16);
      const unsigned pi = (unsigned)(unsigned short)f2bs(iaf[e]) |
                          ((unsigned)(unsigned short)f2bs(ibf[e]) << 16);
      ((unsigned*)Lr)[d] = pr;
      ((unsigned*)Li)[d] = pi;
    }
  }
  __syncthreads();

  const floatx4 zero = {0.f, 0.f, 0.f, 0.f};
  #pragma unroll 1
  for (int ct = 0; ct < 6; ++ct) {
    floatx4 Cr = zero, Ci = zero;
    #pragma unroll
    for (int kk = 0; kk < 2; ++kk) {
      const int a = (ct*16 + qm) * 72 + kk*32 + quad*8;
      const short8 sr = *(const short8*)&Lr[a];
      const short8 si = *(const short8*)&Li[a];
      Cr = __builtin_amdgcn_mfma_f32_16x16x32_bf16(Trh[kk],  sr, Cr, 0,0,0);
      Cr = __builtin_amdgcn_mfma_f32_16x16x32_bf16(Trl[kk],  sr, Cr, 0,0,0);
      Cr = __builtin_amdgcn_mfma_f32_16x16x32_bf16(TiNh[kk], si, Cr, 0,0,0);
      Cr = __builtin_amdgcn_mfma_f32_16x16x32_bf16(TiNl[kk], si, Cr, 0,0,0);
      Ci = __builtin_amdgcn_mfma_f32_16x16x32_bf16(Tih[kk],  sr, Ci, 0,0,0);
      Ci = __builtin_amdgcn_mfma_f32_16x16x32_bf16(Til[kk],  sr, Ci, 0,0,0);
      Ci = __builtin_amdgcn_mfma_f32_16x16x32_bf16(Trh[kk],  si, Ci, 0,0,0);
      Ci = __builtin_amdgcn_mfma_f32_16x16x32_bf16(Trl[kk],  si, Ci, 0,0,0);
    }
    #pragma unroll
    for (int r = 0; r < 4; ++r) {
      const int hpo = wave*16 + quad*4 + r;
      const size_t o = base + (size_t)hpo * hstride + c0 + ct*16 + qm;
      Sr[o] = Cr[r];
      Si[o] = Ci[r];
    }
  }
}

// ---------------------------------------------------------------------------
// Kernel P: transpose + convert mixing weights to bf16 B^T fragments.
// ---------------------------------------------------------------------------
__global__ __launch_bounds__(256) void k_prep_w(
    const float* __restrict__ w1, const float* __restrict__ w2,
    short* __restrict__ Wout)
{
  const int arr = blockIdx.y;
  const int i = blockIdx.x * 256 + threadIdx.x;
  const int nb = i / (BS*BS);
  const int rem = i % (BS*BS);
  const int n = rem / BS;
  const int d = rem % BS;
  const float* src = (arr < 3) ? w1 : w2;
  const int j = ((arr % 3) == 0) ? 0 : 1;
  const float s = ((arr % 3) == 2) ? -1.f : 1.f;
  const float v = s * src[((size_t)(j*NBLK + nb) * BS + d) * BS + n];
  Wout[(size_t)arr * (NBLK*BS*BS) + i] = f2bs(v);
}

// ---------------------------------------------------------------------------
// Kernel 4 (v2): block-complex 2-layer MLP via MFMA bf16, fp32 accumulate.
// ---------------------------------------------------------------------------
__global__ __launch_bounds__(256) void k_mix2(
    float* __restrict__ Sr, float* __restrict__ Si,
    const short* __restrict__ WT,
    const float* __restrict__ b1, const float* __restrict__ b2)
{
  __shared__ short Ar[64 * LROW];
  __shared__ short Ai[64 * LROW];
  const int t = threadIdx.x;
  const int wave = t >> 6, lane = t & 63;
  const int qm = lane & 15, quad = lane >> 4;
  const int nb = blockIdx.y;
  const int row0 = blockIdx.x * 64;

  const int WSZ = NBLK * BS * BS;
  const short* W1R  = WT;
  const short* W1I  = WT + 1 * WSZ;
  const short* W1IN = WT + 2 * WSZ;
  const short* W2R  = WT + 3 * WSZ;
  const short* W2I  = WT + 4 * WSZ;
  const short* W2IN = WT + 5 * WSZ;

  {
    const float4* Sr4 = (const float4*)Sr;
    const float4* Si4 = (const float4*)Si;
    #pragma unroll
    for (int it = 0; it < 12; ++it) {
      const int i = t + it * 256;
      const int r = i / 48, c4 = i % 48;
      const size_t g = (size_t)(row0 + r) * (DIM/4) + nb * 48 + c4;
      const float4 vr = Sr4[g], vi = Si4[g];
      short4v pr = { f2bs(vr.x), f2bs(vr.y), f2bs(vr.z), f2bs(vr.w) };
      short4v pi = { f2bs(vi.x), f2bs(vi.y), f2bs(vi.z), f2bs(vi.w) };
      *(short4v*)&Ar[r * LROW + c4 * 4] = pr;
      *(short4v*)&Ai[r * LROW + c4 * 4] = pi;
    }
  }
  __syncthreads();

  int nl[3];
  size_t wb[3];
  #pragma unroll
  for (int nt = 0; nt < 3; ++nt) {
    nl[nt] = wave * 48 + nt * 16 + qm;
    wb[nt] = (size_t)(nb * BS + nl[nt]) * BS + quad * 8;
  }
  const floatx4 zero = {0.f, 0.f, 0.f, 0.f};

  floatx4 aR[4][3], aI[4][3];
  #pragma unroll
  for (int ms = 0; ms < 4; ++ms)
    #pragma unroll
    for (int nt = 0; nt < 3; ++nt) { aR[ms][nt] = zero; aI[ms][nt] = zero; }

  #pragma unroll 1
  for (int k0 = 0; k0 < BS; k0 += 32) {
    short8 xr[4], xi[4];
    #pragma unroll
    for (int ms = 0; ms < 4; ++ms) {
      const int a = (ms*16 + qm) * LROW + k0 + quad * 8;
      xr[ms] = *(const short8*)&Ar[a];
      xi[ms] = *(const short8*)&Ai[a];
    }
    #pragma unroll
    for (int nt = 0; nt < 3; ++nt) {
      const short8 br  = *(const short8*)&W1R [wb[nt] + k0];
      const short8 bi  = *(const short8*)&W1I [wb[nt] + k0];
      const short8 bin = *(const short8*)&W1IN[wb[nt] + k0];
      #pragma unroll
      for (int ms = 0; ms < 4; ++ms) {
        aR[ms][nt] = __builtin_amdgcn_mfma_f32_16x16x32_bf16(xr[ms], br,  aR[ms][nt], 0,0,0);
        aR[ms][nt] = __builtin_amdgcn_mfma_f32_16x16x32_bf16(xi[ms], bin, aR[ms][nt], 0,0,0);
        aI[ms][nt] = __builtin_amdgcn_mfma_f32_16x16x32_bf16(xr[ms], bi,  aI[ms][nt], 0,0,0);
        aI[ms][nt] = __builtin_amdgcn_mfma_f32_16x16x32_bf16(xi[ms], br,  aI[ms][nt], 0,0,0);
      }
    }
  }
  __syncthreads();
  #pragma unroll
  for (int nt = 0; nt < 3; ++nt) {
    const float b1r = b1[nb * BS + nl[nt]];
    const float b1i = b1[(NBLK + nb) * BS + nl[nt]];
    #pragma unroll
    for (int ms = 0; ms < 4; ++ms)
      #pragma unroll
      for (int r = 0; r < 4; ++r) {
        const int row = ms*16 + quad*4 + r;
        Ar[row * LROW + nl[nt]] = f2bs(fmaxf(aR[ms][nt][r] + b1r, 0.f));
        Ai[row * LROW + nl[nt]] = f2bs(fmaxf(aI[ms][nt][r] + b1i, 0.f));
      }
  }
  __syncthreads();

  floatx4 aR2[4][3];
  #pragma unroll
  for (int ms = 0; ms < 4; ++ms)
    #pragma unroll
    for (int nt = 0; nt < 3; ++nt) aR2[ms][nt] = zero;

  #pragma unroll 1
  for (int k0 = 0; k0 < BS; k0 += 32) {
    short8 r1[4], i1[4];
    #pragma unroll
    for (int ms = 0; ms < 4; ++ms) {
      const int a = (ms*16 + qm) * LROW + k0 + quad * 8;
      r1[ms] = *(const short8*)&Ar[a];
      i1[ms] = *(const short8*)&Ai[a];
    }
    #pragma unroll
    for (int nt = 0; nt < 3; ++nt) {
      const short8 br  = *(const short8*)&W2R [wb[nt] + k0];
      const short8 bin = *(const short8*)&W2IN[wb[nt] + k0];
      #pragma unroll
      for (int ms = 0; ms < 4; ++ms) {
        aR2[ms][nt] = __builtin_amdgcn_mfma_f32_16x16x32_bf16(r1[ms], br,  aR2[ms][nt], 0,0,0);
        aR2[ms][nt] = __builtin_amdgcn_mfma_f32_16x16x32_bf16(i1[ms], bin, aR2[ms][nt], 0,0,0);
      }
    }
  }
  __syncthreads();
  #pragma unroll
  for (int nt = 0; nt < 3; ++nt) {
    const float b2r = b2[nb * BS + nl[nt]];
    #pragma unroll
    for (int ms = 0; ms < 4; ++ms)
      #pragma unroll
      for (int r = 0; r < 4; ++r) {
        const int row = ms*16 + quad*4 + r;
        const float R2 = aR2[ms][nt][r] + b2r;
        Sr[(size_t)(row0 + row) * DIM + nb * BS + nl[nt]] = R2;
        Ar[row * LROW + nl[nt]] = f2bs(R2);
      }
  }
  __syncthreads();

  floatx4 aI2[4][3];
  #pragma unroll
  for (int ms = 0; ms < 4; ++ms)
    #pragma unroll
    for (int nt = 0; nt < 3; ++nt) aI2[ms][nt] = zero;

  #pragma unroll 1
  for (int k0 = 0; k0 < BS; k0 += 32) {
    short8 r2[4], i1[4];
    #pragma unroll
    for (int ms = 0; ms < 4; ++ms) {
      const int a = (ms*16 + qm) * LROW + k0 + quad * 8;
      r2[ms] = *(const short8*)&Ar[a];
      i1[ms] = *(const short8*)&Ai[a];
    }
    #pragma unroll
    for (int nt = 0; nt < 3; ++nt) {
      const short8 bi = *(const short8*)&W2I[wb[nt] + k0];
      const short8 br = *(const short8*)&W2R[wb[nt] + k0];
      #pragma unroll
      for (int ms = 0; ms < 4; ++ms) {
        aI2[ms][nt] = __builtin_amdgcn_mfma_f32_16x16x32_bf16(r2[ms], bi, aI2[ms][nt], 0,0,0);
        aI2[ms][nt] = __builtin_amdgcn_mfma_f32_16x16x32_bf16(i1[ms], br, aI2[ms][nt], 0,0,0);
      }
    }
  }
  #pragma unroll
  for (int nt = 0; nt < 3; ++nt) {
    const float b2i = b2[(NBLK + nb) * BS + nl[nt]];
    #pragma unroll
    for (int ms = 0; ms < 4; ++ms)
      #pragma unroll
      for (int r = 0; r < 4; ++r) {
        const int row = ms*16 + quad*4 + r;
        Si[(size_t)(row0 + row) * DIM + nb * BS + nl[nt]] = aI2[ms][nt][r] + b2i;
      }
  }
}

// ---------------------------------------------------------------------------
// Kernel 6 (v2): c2r inverse along k as MFMA GEMM + bias partial add.
// out[w,c] = sum_k (ck*cos(wk)/64)*gr[k,c] + (-ck*sin(wk)/64)*gi[k,c], k padded to 64.
// ---------------------------------------------------------------------------
__global__ __launch_bounds__(256) void k_irfft_w_mfma(
    const float* __restrict__ Sr, const float* __restrict__ Si,
    float* __restrict__ out)
{
  __shared__ short Lr[96 * 72];   // [c][k], zero-padded k>=33
  __shared__ short Li[96 * 72];
  const int t = threadIdx.x;
  const int wave = t >> 6, lane = t & 63;
  const int qm = lane & 15, quad = lane >> 4;
  const int bh = blockIdx.x;
  const int c0 = blockIdx.y * 96;
  const size_t gbase = (size_t)bh * (KH*DIM);
  const size_t obase = (size_t)bh * (WW*DIM);

  // stage g -> LDS transposed [c][k] bf16, zero pad beyond k=32
  #pragma unroll
  for (int it = 0; it < 3; ++it) {
    const int i = t + it * 256;
    const int hd = i & 31;              // k-pair: 2hd, 2hd+1
    const int c4 = i >> 5;
    const int ka = 2*hd, kb = 2*hd + 1;
    float4 ra = {0.f,0.f,0.f,0.f}, rb = ra, ia = ra, ib = ra;
    if (ka < KH) {
      const size_t g0 = gbase + (size_t)ka * DIM + c0 + c4 * 4;
      ra = *(const float4*)&Sr[g0];
      ia = *(const float4*)&Si[g0];
    }
    if (kb < KH) {
      const size_t g1 = gbase + (size_t)kb * DIM + c0 + c4 * 4;
      rb = *(const float4*)&Sr[g1];
      ib = *(const float4*)&Si[g1];
    }
    const float raf[4] = {ra.x, ra.y, ra.z, ra.w};
    const float rbf[4] = {rb.x, rb.y, rb.z, rb.w};
    const float iaf[4] = {ia.x, ia.y, ia.z, ia.w};
    const float ibf[4] = {ib.x, ib.y, ib.z, ib.w};
    #pragma unroll
    for (int e = 0; e < 4; ++e) {
      const int d = (c4*4 + e) * 36 + hd;
      ((unsigned*)Lr)[d] = (unsigned)(unsigned short)f2bs(raf[e]) |
                           ((unsigned)(unsigned short)f2bs(rbf[e]) << 16);
      ((unsigned*)Li)[d] = (unsigned)(unsigned short)f2bs(iaf[e]) |
                           ((unsigned)(unsigned short)f2bs(ibf[e]) << 16);
    }
  }

  // twiddle A-frags: m=w (qm), k-dim = k bin (quad*8+j+32kk); ck & 1/64 folded
  short8 Arh[2], Arl[2], Aih[2], Ail[2];
  const int wrow = wave * 16 + qm;
  #pragma unroll
  for (int kk = 0; kk < 2; ++kk) {
    #pragma unroll
    for (int j = 0; j < 8; ++j) {
      const int k = quad * 8 + j + kk * 32;
      float ar = 0.f, ai = 0.f;
      if (k < KH) {
        const int ph = (wrow * k) & 63;
        float s, c;
        sincosf((float)ph * TWOPI_OVER_64, &s, &c);
        const float ck = (k == 0 || k == 32) ? (1.0f/64.0f) : (2.0f/64.0f);
        ar = ck * c;
        ai = -ck * s;
      }
      const short arh = f2bs(ar);
      const short aih = f2bs(ai);
      Arh[kk][j] = arh;  Arl[kk][j] = f2bs(ar - bs2f(arh));
      Aih[kk][j] = aih;  Ail[kk][j] = f2bs(ai - bs2f(aih));
    }
  }
  __syncthreads();

  const floatx4 zero = {0.f, 0.f, 0.f, 0.f};
  #pragma unroll 1
  for (int ct = 0; ct < 6; ++ct) {
    floatx4 C = zero;
    #pragma unroll
    for (int kk = 0; kk < 2; ++kk) {
      const int a = (ct*16 + qm) * 72 + kk*32 + quad*8;
      const short8 gr = *(const short8*)&Lr[a];
      const short8 gi = *(const short8*)&Li[a];
      C = __builtin_amdgcn_mfma_f32_16x16x32_bf16(Arh[kk], gr, C, 0,0,0);
      C = __builtin_amdgcn_mfma_f32_16x16x32_bf16(Arl[kk], gr, C, 0,0,0);
      C = __builtin_amdgcn_mfma_f32_16x16x32_bf16(Aih[kk], gi, C, 0,0,0);
      C = __builtin_amdgcn_mfma_f32_16x16x32_bf16(Ail[kk], gi, C, 0,0,0);
    }
    #pragma unroll
    for (int r = 0; r < 4; ++r) {
      const int w = wave*16 + quad*4 + r;
      const size_t o = obase + (size_t)w * DIM + c0 + ct*16 + qm;
      out[o] += C[r];    // add bias partial from k_bias_gemm2
    }
  }
}

// ---------------------------------------------------------------------------
extern "C" void kernel_launch(void* const* d_in, const int* in_sizes, int n_in,
                              void* d_out, int out_size, void* d_ws, size_t ws_size,
                              hipStream_t stream) {
  const float* x  = (const float*)d_in[0];
  const float* w1 = (const float*)d_in[1];
  const float* b1 = (const float*)d_in[2];
  const float* w2 = (const float*)d_in[3];
  const float* b2 = (const float*)d_in[4];
  const float* bw = (const float*)d_in[5];
  const float* bb = (const float*)d_in[6];
  float* out = (float*)d_out;

  float* Sr = (float*)d_ws;
  float* Si = Sr + (size_t)NPTS * DIM;
  short* WT = (short*)(Si + (size_t)NPTS * DIM);

  // P) transpose+convert mixing weights to bf16 fragments
  k_prep_w<<<dim3((NBLK*BS*BS)/256, 6), 256, 0, stream>>>(w1, w2, WT);
  // 1) bias = x @ bias_w^T + bias_b  -> d_out (fp32 partial)
  k_bias_gemm2<<<dim3(32768/128, DIM/128), 256, 0, stream>>>(x, bw, bb, out);
  // 2) forward rfft along w via MFMA (unnormalized)
  k_rfft_w_mfma<<<dim3(BATCH*HH, DIM/96), 256, 0, stream>>>(x, Sr, Si);
  // 3) forward fft along h via MFMA (ortho scale 1/64 folded into twiddles)
  k_fft_h_mfma<-1><<<dim3(BATCH*KH, DIM/96), 256, 0, stream>>>(Sr, Si, 1.0f/64.0f);
  // 4) block-complex MLP mixing via MFMA, in place
  k_mix2<<<dim3(NPTS/64, NBLK), 256, 0, stream>>>(Sr, Si, WT, b1, b2);
  // 5) inverse fft along h via MFMA (unnormalized)
  k_fft_h_mfma<+1><<<dim3(BATCH*KH, DIM/96), 256, 0, stream>>>(Sr, Si, 1.0f);
  // 6) c2r inverse along k via MFMA + bias partial -> final fp32 output
  k_irfft_w_mfma<<<dim3(BATCH*HH, DIM/96), 256, 0, stream>>>(Sr, Si, out);
}